// Round 5
// baseline (239.647 us; speedup 1.0000x reference)
//
#include <hip/hip_runtime.h>
#include <cstdint>

#define BB 4
#define CDIM 128
#define HH 64
#define WW 64
#define RR 3
#define DD 7
#define DSQ 49

__device__ __forceinline__ int reflect64(int p) {
    p = (p < 0) ? -p : p;
    return (p > 63) ? (126 - p) : p;
}
__device__ __forceinline__ float sigm(float x) { return 1.0f / (1.0f + __expf(-x)); }

// ---- conv1x1(128->128) -> LN(128) -> [SiLU] -> conv1x1(128->128), one (b,h) row per block
// 1024 threads = 16 waves; wave q owns 8 output channels.
template<bool SILU>
__global__ __launch_bounds__(1024) void proj_kernel(
    const float* __restrict__ x, const float* __restrict__ w1,
    const float* __restrict__ b1, const float* __restrict__ lnw,
    const float* __restrict__ lnb, const float* __restrict__ w2,
    const float* __restrict__ b2, float* __restrict__ out)
{
    __shared__ float sX[CDIM][WW];
    __shared__ float sY[CDIM][WW];
    __shared__ float red1[16][WW];
    __shared__ float red2[16][WW];

    const int tid = threadIdx.x;
    const int w = tid & 63;
    const int q = tid >> 6;        // 0..15, wave id
    const int b = blockIdx.x >> 6;
    const int h = blockIdx.x & 63;

    const float* xrow = x + (b * CDIM * HH + h) * WW;
    for (int idx = tid; idx < CDIM * WW; idx += 1024)
        sX[idx >> 6][idx & 63] = xrow[(idx >> 6) * HH * WW + (idx & 63)];
    __syncthreads();

    float acc[8];
    #pragma unroll
    for (int k = 0; k < 8; ++k) acc[k] = b1[q * 8 + k];
    for (int i = 0; i < CDIM; i += 4) {
        float x0 = sX[i][w], x1 = sX[i+1][w], x2 = sX[i+2][w], x3 = sX[i+3][w];
        #pragma unroll
        for (int k = 0; k < 8; ++k) {
            const float4 wv = *reinterpret_cast<const float4*>(&w1[(q*8+k)*CDIM + i]);
            acc[k] = fmaf(wv.x, x0, fmaf(wv.y, x1, fmaf(wv.z, x2, fmaf(wv.w, x3, acc[k]))));
        }
    }
    float s1 = 0.f, s2 = 0.f;
    #pragma unroll
    for (int k = 0; k < 8; ++k) { s1 += acc[k]; s2 += acc[k] * acc[k]; }
    red1[q][w] = s1; red2[q][w] = s2;
    __syncthreads();
    float t1 = 0.f, t2 = 0.f;
    #pragma unroll
    for (int j = 0; j < 16; ++j) { t1 += red1[j][w]; t2 += red2[j][w]; }
    const float mean = t1 * (1.0f / 128.0f);
    const float var  = t2 * (1.0f / 128.0f) - mean * mean;
    const float rstd = rsqrtf(var + 1e-6f);
    #pragma unroll
    for (int k = 0; k < 8; ++k) {
        const int o = q * 8 + k;
        float v = (acc[k] - mean) * rstd * lnw[o] + lnb[o];
        if (SILU) v = v * sigm(v);
        sY[o][w] = v;
    }
    __syncthreads();
    float acc2[8];
    #pragma unroll
    for (int k = 0; k < 8; ++k) acc2[k] = b2[q * 8 + k];
    for (int i = 0; i < CDIM; i += 4) {
        float x0 = sY[i][w], x1 = sY[i+1][w], x2 = sY[i+2][w], x3 = sY[i+3][w];
        #pragma unroll
        for (int k = 0; k < 8; ++k) {
            const float4 wv = *reinterpret_cast<const float4*>(&w2[(q*8+k)*CDIM + i]);
            acc2[k] = fmaf(wv.x, x0, fmaf(wv.y, x1, fmaf(wv.z, x2, fmaf(wv.w, x3, acc2[k]))));
        }
    }
    float* orow = out + (b * CDIM * HH + h) * WW;
    #pragma unroll
    for (int k = 0; k < 8; ++k)
        orow[(q * 8 + k) * HH * WW + w] = acc2[k];
}

// ---- sim = <patch, center>/sqrt(C); softmax over 49; * gaussian spatial kernel
// 1024 threads; wave q handles n = q + 16*k, k<4.
__global__ __launch_bounds__(1024) void simsoftmax_kernel(
    const float* __restrict__ px, const float* __restrict__ sigma_p,
    float* __restrict__ combined)
{
    __shared__ float sP[32][DD * WW];   // 32-channel chunk, 7 reflected rows
    __shared__ float sSim[DSQ][WW];

    const int tid = threadIdx.x;
    const int w = tid & 63;
    const int q = tid >> 6;            // 0..15
    const int b = blockIdx.x >> 6;
    const int h = blockIdx.x & 63;

    int offk[4];
    #pragma unroll
    for (int k = 0; k < 4; ++k) {
        int n = q + 16 * k; if (n > 48) n = 48;   // clamp (garbage lanes never written back)
        const int ki = n / 7, kj = n % 7;
        offk[k] = ki * WW + reflect64(w + kj - RR);
    }

    float sim[4];
    #pragma unroll
    for (int k = 0; k < 4; ++k) sim[k] = 0.f;

    const float* pb = px + b * CDIM * HH * WW;
    for (int cc = 0; cc < 4; ++cc) {
        __syncthreads();
        for (int idx = tid; idx < 32 * DD * WW; idx += 1024) {
            const int ww = idx & 63;
            const int rest = idx >> 6;      // 0..223
            const int ki = rest % DD;
            const int cl = rest / DD;
            const int hp = reflect64(h + ki - RR);
            sP[cl][ki * WW + ww] = pb[(cc * 32 + cl) * HH * WW + hp * WW + ww];
        }
        __syncthreads();
        for (int cl = 0; cl < 32; ++cl) {
            const float xc = sP[cl][RR * WW + w];
            #pragma unroll
            for (int k = 0; k < 4; ++k)
                sim[k] = fmaf(sP[cl][offk[k]], xc, sim[k]);
        }
    }

    const float rscale = 0.088388347648318447f;  // 1/sqrt(128)
    #pragma unroll
    for (int k = 0; k < 4; ++k) {
        const int n = q + 16 * k;
        if (n < DSQ) sSim[n][w] = sim[k] * rscale;
    }
    __syncthreads();
    float m = -1e30f;
    for (int n = 0; n < DSQ; ++n) m = fmaxf(m, sSim[n][w]);
    float ssum = 0.f;
    for (int n = 0; n < DSQ; ++n) ssum += __expf(sSim[n][w] - m);
    const float inv = 1.0f / ssum;
    const float sigma = sigma_p[0];
    const float inv2s2 = 1.0f / (2.0f * sigma * sigma);
    float* cb = combined + (b * DSQ * HH + h) * WW;
    #pragma unroll
    for (int k = 0; k < 4; ++k) {
        const int n = q + 16 * k;
        if (n < DSQ) {
            const int ki = n / 7, kj = n % 7;
            const float dx = (float)(ki - 3) * (1.0f / 3.0f);
            const float dy = (float)(kj - 3) * (1.0f / 3.0f);
            const float sk = __expf(-(dx * dx + dy * dy) * inv2s2);
            cb[n * HH * WW + w] = __expf(sim[k] * rscale - m) * inv * sk;
        }
    }
}

// ---- fixup: conv(177->49) -> LN(49) -> SiLU -> conv(49->49) -> gate -> normalize
// 1024 threads; wave q handles o = q + 16*k, k<4.
__global__ __launch_bounds__(1024) void fixup_kernel(
    const float* __restrict__ combined, const float* __restrict__ sem,
    const float* __restrict__ w1, const float* __restrict__ b1,
    const float* __restrict__ lnw, const float* __restrict__ lnb,
    const float* __restrict__ w2, const float* __restrict__ b2,
    float* __restrict__ wts)
{
    __shared__ float sCmb[DSQ][WW];
    __shared__ float sSem[CDIM][WW];
    __shared__ float sG[DSQ][WW];
    __shared__ float red1[16][WW];

    const int tid = threadIdx.x;
    const int w = tid & 63;
    const int q = tid >> 6;            // 0..15
    const int b = blockIdx.x >> 6;
    const int h = blockIdx.x & 63;

    const float* crow = combined + (b * DSQ * HH + h) * WW;
    for (int idx = tid; idx < DSQ * WW; idx += 1024)
        sCmb[idx >> 6][idx & 63] = crow[(idx >> 6) * HH * WW + (idx & 63)];
    const float* srow = sem + (b * CDIM * HH + h) * WW;
    for (int idx = tid; idx < CDIM * WW; idx += 1024)
        sSem[idx >> 6][idx & 63] = srow[(idx >> 6) * HH * WW + (idx & 63)];
    __syncthreads();

    float g[4];
    #pragma unroll
    for (int k = 0; k < 4; ++k) {
        int o = q + 16 * k; if (o > 48) o = 48;
        g[k] = b1[o];
    }
    for (int i = 0; i < DSQ; ++i) {
        const float xv = sCmb[i][w];
        #pragma unroll
        for (int k = 0; k < 4; ++k) {
            int o = q + 16 * k; if (o > 48) o = 48;
            g[k] = fmaf(w1[o * 177 + i], xv, g[k]);
        }
    }
    for (int c = 0; c < CDIM; ++c) {
        const float xv = sSem[c][w];
        #pragma unroll
        for (int k = 0; k < 4; ++k) {
            int o = q + 16 * k; if (o > 48) o = 48;
            g[k] = fmaf(w1[o * 177 + DSQ + c], xv, g[k]);
        }
    }
    float s1 = 0.f, s2 = 0.f;
    #pragma unroll
    for (int k = 0; k < 4; ++k)
        if (q + 16 * k < DSQ) { s1 += g[k]; s2 += g[k] * g[k]; }
    red1[q][w] = s1;
    __syncthreads();
    float t1 = 0.f;
    #pragma unroll
    for (int j = 0; j < 16; ++j) t1 += red1[j][w];
    __syncthreads();
    red1[q][w] = s2;
    __syncthreads();
    float t2 = 0.f;
    #pragma unroll
    for (int j = 0; j < 16; ++j) t2 += red1[j][w];
    const float mean = t1 * (1.0f / 49.0f);
    const float var  = t2 * (1.0f / 49.0f) - mean * mean;
    const float rstd = rsqrtf(var + 1e-6f);
    #pragma unroll
    for (int k = 0; k < 4; ++k) {
        const int o = q + 16 * k;
        if (o < DSQ) {
            float v = (g[k] - mean) * rstd * lnw[o] + lnb[o];
            sG[o][w] = v * sigm(v);
        }
    }
    __syncthreads();
    float f[4];
    #pragma unroll
    for (int k = 0; k < 4; ++k) {
        int o = q + 16 * k; if (o > 48) o = 48;
        f[k] = b2[o];
    }
    for (int i = 0; i < DSQ; ++i) {
        const float xv = sG[i][w];
        #pragma unroll
        for (int k = 0; k < 4; ++k) {
            int o = q + 16 * k; if (o > 48) o = 48;
            f[k] = fmaf(w2[o * DSQ + i], xv, f[k]);
        }
    }
    float c2[4];
    float ps = 0.f;
    #pragma unroll
    for (int k = 0; k < 4; ++k) {
        const int o = q + 16 * k;
        if (o < DSQ) {
            c2[k] = sCmb[o][w] * (1.0f + sigm(f[k]));
            ps += c2[k];
        } else c2[k] = 0.f;
    }
    __syncthreads();
    red1[q][w] = ps;
    __syncthreads();
    float tot = 0.f;
    #pragma unroll
    for (int j = 0; j < 16; ++j) tot += red1[j][w];
    const float invt = 1.0f / (tot + 1e-7f);
    float* wrow = wts + (b * DSQ * HH + h) * WW;
    #pragma unroll
    for (int k = 0; k < 4; ++k) {
        const int o = q + 16 * k;
        if (o < DSQ) wrow[o * HH * WW + w] = c2[k] * invt;
    }
}

// ---- out0[c] = sum_n spatial[c, nbr(n)] * wts[n]
// 1024 threads; wave q owns 2 channels per 32-channel chunk.
__global__ __launch_bounds__(1024) void aggregate_kernel(
    const float* __restrict__ spatial, const float* __restrict__ wts,
    float* __restrict__ out)
{
    __shared__ float sS[32][DD * WW];
    __shared__ float sWts[DSQ][WW];

    const int tid = threadIdx.x;
    const int w = tid & 63;
    const int q = tid >> 6;            // 0..15
    const int b = blockIdx.x >> 6;
    const int h = blockIdx.x & 63;

    const float* wrow = wts + (b * DSQ * HH + h) * WW;
    for (int idx = tid; idx < DSQ * WW; idx += 1024)
        sWts[idx >> 6][idx & 63] = wrow[(idx >> 6) * HH * WW + (idx & 63)];

    const float* sb = spatial + b * CDIM * HH * WW;
    float* orow = out + (b * CDIM * HH + h) * WW;

    for (int cc = 0; cc < 4; ++cc) {
        __syncthreads();
        for (int idx = tid; idx < 32 * DD * WW; idx += 1024) {
            const int ww = idx & 63;
            const int rest = idx >> 6;
            const int ki = rest % DD;
            const int cl = rest / DD;
            const int hp = reflect64(h + ki - RR);
            sS[cl][ki * WW + ww] = sb[(cc * 32 + cl) * HH * WW + hp * WW + ww];
        }
        __syncthreads();
        float acc[2] = {0.f, 0.f};
        for (int n = 0; n < DSQ; ++n) {
            const int ki = n / 7, kj = n % 7;
            const int off = ki * WW + reflect64(w + kj - RR);
            const float wv = sWts[n][w];
            #pragma unroll
            for (int j = 0; j < 2; ++j)
                acc[j] = fmaf(sS[q * 2 + j][off], wv, acc[j]);
        }
        #pragma unroll
        for (int j = 0; j < 2; ++j)
            orow[(cc * 32 + q * 2 + j) * HH * WW + w] = acc[j];
    }
}

extern "C" void kernel_launch(void* const* d_in, const int* in_sizes, int n_in,
                              void* d_out, int out_size, void* d_ws, size_t ws_size,
                              hipStream_t stream) {
    (void)in_sizes; (void)n_in; (void)out_size; (void)ws_size;
    const float* spatial  = (const float*)d_in[0];
    const float* semantic = (const float*)d_in[1];
    const float* rp_w1 = (const float*)d_in[2];
    const float* rp_b1 = (const float*)d_in[3];
    const float* rp_lnw = (const float*)d_in[4];
    const float* rp_lnb = (const float*)d_in[5];
    const float* rp_w2 = (const float*)d_in[6];
    const float* rp_b2 = (const float*)d_in[7];
    const float* fx_w1 = (const float*)d_in[8];
    const float* fx_b1 = (const float*)d_in[9];
    const float* fx_lnw = (const float*)d_in[10];
    const float* fx_lnb = (const float*)d_in[11];
    const float* fx_w2 = (const float*)d_in[12];
    const float* fx_b2 = (const float*)d_in[13];
    const float* sigma = (const float*)d_in[14];
    const float* op_w1 = (const float*)d_in[15];
    const float* op_b1 = (const float*)d_in[16];
    const float* op_lnw = (const float*)d_in[17];
    const float* op_lnb = (const float*)d_in[18];
    const float* op_w2 = (const float*)d_in[19];
    const float* op_b2 = (const float*)d_in[20];

    float* ws = (float*)d_ws;
    float* proj_x   = ws;                       // 2,097,152 floats
    float* combined = ws + 2097152;             //   802,816 floats
    float* wtsbuf   = ws + 2899968;             //   802,816 floats
    float* agg      = proj_x;                   // reuse (proj_x dead after simsoftmax)
    float* outp     = (float*)d_out;

    dim3 grid(BB * HH), blk(1024);
    proj_kernel<true><<<grid, blk, 0, stream>>>(semantic, rp_w1, rp_b1, rp_lnw, rp_lnb,
                                                rp_w2, rp_b2, proj_x);
    simsoftmax_kernel<<<grid, blk, 0, stream>>>(proj_x, sigma, combined);
    fixup_kernel<<<grid, blk, 0, stream>>>(combined, semantic, fx_w1, fx_b1, fx_lnw,
                                           fx_lnb, fx_w2, fx_b2, wtsbuf);
    aggregate_kernel<<<grid, blk, 0, stream>>>(spatial, wtsbuf, agg);
    proj_kernel<false><<<grid, blk, 0, stream>>>(agg, op_w1, op_b1, op_lnw, op_lnb,
                                                 op_w2, op_b2, outp);
}

// Round 6
// 195.461 us; speedup vs baseline: 1.2261x; 1.2261x over previous
//
#include <hip/hip_runtime.h>
#include <cstdint>

#define BB 4
#define CDIM 128
#define HH 64
#define WW 64
#define RR 3
#define DD 7
#define DSQ 49

__device__ __forceinline__ int reflect64(int p) {
    p = (p < 0) ? -p : p;
    return (p > 63) ? (126 - p) : p;
}
__device__ __forceinline__ float sigm(float x) { return 1.0f / (1.0f + __expf(-x)); }

// ---- conv1x1(128->128) -> LN(128) -> [SiLU] -> conv1x1(128->128), one (b,h) row per block
// 1024 threads = 16 waves; wave q owns 8 output channels.
// Weight/bias/LN indices are readfirstlane'd -> scalar s_load, freeing VGPRs and
// letting the compiler pipeline weight fetches across iterations.
template<bool SILU>
__global__ __launch_bounds__(1024) void proj_kernel(
    const float* __restrict__ x, const float* __restrict__ w1,
    const float* __restrict__ b1, const float* __restrict__ lnw,
    const float* __restrict__ lnb, const float* __restrict__ w2,
    const float* __restrict__ b2, float* __restrict__ out)
{
    __shared__ float sX[CDIM][WW];
    __shared__ float sY[CDIM][WW];
    __shared__ float red1[16][WW];
    __shared__ float red2[16][WW];

    const int tid = threadIdx.x;
    const int w = tid & 63;
    const int q = tid >> 6;        // 0..15, wave id
    const int qu = __builtin_amdgcn_readfirstlane(q);   // wave-uniform (scalar)
    const int b = blockIdx.x >> 6;
    const int h = blockIdx.x & 63;

    const float* xrow = x + (b * CDIM * HH + h) * WW;
    for (int idx = tid; idx < CDIM * WW; idx += 1024)
        sX[idx >> 6][idx & 63] = xrow[(idx >> 6) * HH * WW + (idx & 63)];
    __syncthreads();

    float acc[8];
    #pragma unroll
    for (int k = 0; k < 8; ++k) acc[k] = b1[qu * 8 + k];
    #pragma unroll 2
    for (int i = 0; i < CDIM; i += 4) {
        float x0 = sX[i][w], x1 = sX[i+1][w], x2 = sX[i+2][w], x3 = sX[i+3][w];
        #pragma unroll
        for (int k = 0; k < 8; ++k) {
            const float4 wv = *reinterpret_cast<const float4*>(&w1[(qu*8+k)*CDIM + i]);
            acc[k] = fmaf(wv.x, x0, fmaf(wv.y, x1, fmaf(wv.z, x2, fmaf(wv.w, x3, acc[k]))));
        }
    }
    float s1 = 0.f, s2 = 0.f;
    #pragma unroll
    for (int k = 0; k < 8; ++k) { s1 += acc[k]; s2 += acc[k] * acc[k]; }
    red1[q][w] = s1; red2[q][w] = s2;
    __syncthreads();
    float t1 = 0.f, t2 = 0.f;
    #pragma unroll
    for (int j = 0; j < 16; ++j) { t1 += red1[j][w]; t2 += red2[j][w]; }
    const float mean = t1 * (1.0f / 128.0f);
    const float var  = t2 * (1.0f / 128.0f) - mean * mean;
    const float rstd = rsqrtf(var + 1e-6f);
    #pragma unroll
    for (int k = 0; k < 8; ++k) {
        const int o = qu * 8 + k;
        float v = (acc[k] - mean) * rstd * lnw[o] + lnb[o];
        if (SILU) v = v * sigm(v);
        sY[o][w] = v;
    }
    __syncthreads();
    float acc2[8];
    #pragma unroll
    for (int k = 0; k < 8; ++k) acc2[k] = b2[qu * 8 + k];
    #pragma unroll 2
    for (int i = 0; i < CDIM; i += 4) {
        float x0 = sY[i][w], x1 = sY[i+1][w], x2 = sY[i+2][w], x3 = sY[i+3][w];
        #pragma unroll
        for (int k = 0; k < 8; ++k) {
            const float4 wv = *reinterpret_cast<const float4*>(&w2[(qu*8+k)*CDIM + i]);
            acc2[k] = fmaf(wv.x, x0, fmaf(wv.y, x1, fmaf(wv.z, x2, fmaf(wv.w, x3, acc2[k]))));
        }
    }
    float* orow = out + (b * CDIM * HH + h) * WW;
    #pragma unroll
    for (int k = 0; k < 8; ++k)
        orow[(qu * 8 + k) * HH * WW + w] = acc2[k];
}

// ---- sim = <patch, center>/sqrt(C); softmax over 49; * gaussian spatial kernel
// 1024 threads; wave q handles n = q + 16*k, k<4.
__global__ __launch_bounds__(1024) void simsoftmax_kernel(
    const float* __restrict__ px, const float* __restrict__ sigma_p,
    float* __restrict__ combined)
{
    __shared__ float sP[32][DD * WW];   // 32-channel chunk, 7 reflected rows
    __shared__ float sSim[DSQ][WW];

    const int tid = threadIdx.x;
    const int w = tid & 63;
    const int q = tid >> 6;            // 0..15
    const int b = blockIdx.x >> 6;
    const int h = blockIdx.x & 63;

    int offk[4];
    #pragma unroll
    for (int k = 0; k < 4; ++k) {
        int n = q + 16 * k; if (n > 48) n = 48;   // clamp (garbage lanes never written back)
        const int ki = n / 7, kj = n % 7;
        offk[k] = ki * WW + reflect64(w + kj - RR);
    }

    float sim[4];
    #pragma unroll
    for (int k = 0; k < 4; ++k) sim[k] = 0.f;

    const float* pb = px + b * CDIM * HH * WW;
    for (int cc = 0; cc < 4; ++cc) {
        __syncthreads();
        for (int idx = tid; idx < 32 * DD * WW; idx += 1024) {
            const int ww = idx & 63;
            const int rest = idx >> 6;      // 0..223
            const int ki = rest % DD;
            const int cl = rest / DD;
            const int hp = reflect64(h + ki - RR);
            sP[cl][ki * WW + ww] = pb[(cc * 32 + cl) * HH * WW + hp * WW + ww];
        }
        __syncthreads();
        for (int cl = 0; cl < 32; ++cl) {
            const float xc = sP[cl][RR * WW + w];
            #pragma unroll
            for (int k = 0; k < 4; ++k)
                sim[k] = fmaf(sP[cl][offk[k]], xc, sim[k]);
        }
    }

    const float rscale = 0.088388347648318447f;  // 1/sqrt(128)
    #pragma unroll
    for (int k = 0; k < 4; ++k) {
        const int n = q + 16 * k;
        if (n < DSQ) sSim[n][w] = sim[k] * rscale;
    }
    __syncthreads();
    float m = -1e30f;
    for (int n = 0; n < DSQ; ++n) m = fmaxf(m, sSim[n][w]);
    float ssum = 0.f;
    for (int n = 0; n < DSQ; ++n) ssum += __expf(sSim[n][w] - m);
    const float inv = 1.0f / ssum;
    const float sigma = sigma_p[0];
    const float inv2s2 = 1.0f / (2.0f * sigma * sigma);
    float* cb = combined + (b * DSQ * HH + h) * WW;
    #pragma unroll
    for (int k = 0; k < 4; ++k) {
        const int n = q + 16 * k;
        if (n < DSQ) {
            const int ki = n / 7, kj = n % 7;
            const float dx = (float)(ki - 3) * (1.0f / 3.0f);
            const float dy = (float)(kj - 3) * (1.0f / 3.0f);
            const float sk = __expf(-(dx * dx + dy * dy) * inv2s2);
            cb[n * HH * WW + w] = __expf(sim[k] * rscale - m) * inv * sk;
        }
    }
}

// ---- fixup: conv(177->49) -> LN(49) -> SiLU -> conv(49->49) -> gate -> normalize
// 1024 threads; wave q handles o = q + 16*k, k<4. Weight rows readfirstlane'd -> s_load.
__global__ __launch_bounds__(1024) void fixup_kernel(
    const float* __restrict__ combined, const float* __restrict__ sem,
    const float* __restrict__ w1, const float* __restrict__ b1,
    const float* __restrict__ lnw, const float* __restrict__ lnb,
    const float* __restrict__ w2, const float* __restrict__ b2,
    float* __restrict__ wts)
{
    __shared__ float sCmb[DSQ][WW];
    __shared__ float sSem[CDIM][WW];
    __shared__ float sG[DSQ][WW];
    __shared__ float red1[16][WW];

    const int tid = threadIdx.x;
    const int w = tid & 63;
    const int q = tid >> 6;            // 0..15
    const int qu = __builtin_amdgcn_readfirstlane(q);
    const int b = blockIdx.x >> 6;
    const int h = blockIdx.x & 63;

    const float* crow = combined + (b * DSQ * HH + h) * WW;
    for (int idx = tid; idx < DSQ * WW; idx += 1024)
        sCmb[idx >> 6][idx & 63] = crow[(idx >> 6) * HH * WW + (idx & 63)];
    const float* srow = sem + (b * CDIM * HH + h) * WW;
    for (int idx = tid; idx < CDIM * WW; idx += 1024)
        sSem[idx >> 6][idx & 63] = srow[(idx >> 6) * HH * WW + (idx & 63)];
    __syncthreads();

    int ok[4];
    #pragma unroll
    for (int k = 0; k < 4; ++k) {
        int o = qu + 16 * k; if (o > 48) o = 48;   // scalar clamp
        ok[k] = o;
    }

    float g[4];
    #pragma unroll
    for (int k = 0; k < 4; ++k) g[k] = b1[ok[k]];
    #pragma unroll 2
    for (int i = 0; i < DSQ; ++i) {
        const float xv = sCmb[i][w];
        #pragma unroll
        for (int k = 0; k < 4; ++k)
            g[k] = fmaf(w1[ok[k] * 177 + i], xv, g[k]);
    }
    #pragma unroll 2
    for (int c = 0; c < CDIM; ++c) {
        const float xv = sSem[c][w];
        #pragma unroll
        for (int k = 0; k < 4; ++k)
            g[k] = fmaf(w1[ok[k] * 177 + DSQ + c], xv, g[k]);
    }
    float s1 = 0.f, s2 = 0.f;
    #pragma unroll
    for (int k = 0; k < 4; ++k)
        if (q + 16 * k < DSQ) { s1 += g[k]; s2 += g[k] * g[k]; }
    red1[q][w] = s1;
    __syncthreads();
    float t1 = 0.f;
    #pragma unroll
    for (int j = 0; j < 16; ++j) t1 += red1[j][w];
    __syncthreads();
    red1[q][w] = s2;
    __syncthreads();
    float t2 = 0.f;
    #pragma unroll
    for (int j = 0; j < 16; ++j) t2 += red1[j][w];
    const float mean = t1 * (1.0f / 49.0f);
    const float var  = t2 * (1.0f / 49.0f) - mean * mean;
    const float rstd = rsqrtf(var + 1e-6f);
    #pragma unroll
    for (int k = 0; k < 4; ++k) {
        const int o = q + 16 * k;
        if (o < DSQ) {
            float v = (g[k] - mean) * rstd * lnw[ok[k]] + lnb[ok[k]];
            sG[o][w] = v * sigm(v);
        }
    }
    __syncthreads();
    float f[4];
    #pragma unroll
    for (int k = 0; k < 4; ++k) f[k] = b2[ok[k]];
    #pragma unroll 2
    for (int i = 0; i < DSQ; ++i) {
        const float xv = sG[i][w];
        #pragma unroll
        for (int k = 0; k < 4; ++k)
            f[k] = fmaf(w2[ok[k] * DSQ + i], xv, f[k]);
    }
    float c2[4];
    float ps = 0.f;
    #pragma unroll
    for (int k = 0; k < 4; ++k) {
        const int o = q + 16 * k;
        if (o < DSQ) {
            c2[k] = sCmb[o][w] * (1.0f + sigm(f[k]));
            ps += c2[k];
        } else c2[k] = 0.f;
    }
    __syncthreads();
    red1[q][w] = ps;
    __syncthreads();
    float tot = 0.f;
    #pragma unroll
    for (int j = 0; j < 16; ++j) tot += red1[j][w];
    const float invt = 1.0f / (tot + 1e-7f);
    float* wrow = wts + (b * DSQ * HH + h) * WW;
    #pragma unroll
    for (int k = 0; k < 4; ++k) {
        const int o = q + 16 * k;
        if (o < DSQ) wrow[o * HH * WW + w] = c2[k] * invt;
    }
}

// ---- out0[c] = sum_n spatial[c, nbr(n)] * wts[n]
// 1024 threads; wave q owns 2 channels per 32-channel chunk.
__global__ __launch_bounds__(1024) void aggregate_kernel(
    const float* __restrict__ spatial, const float* __restrict__ wts,
    float* __restrict__ out)
{
    __shared__ float sS[32][DD * WW];
    __shared__ float sWts[DSQ][WW];

    const int tid = threadIdx.x;
    const int w = tid & 63;
    const int q = tid >> 6;            // 0..15
    const int b = blockIdx.x >> 6;
    const int h = blockIdx.x & 63;

    const float* wrow = wts + (b * DSQ * HH + h) * WW;
    for (int idx = tid; idx < DSQ * WW; idx += 1024)
        sWts[idx >> 6][idx & 63] = wrow[(idx >> 6) * HH * WW + (idx & 63)];

    const float* sb = spatial + b * CDIM * HH * WW;
    float* orow = out + (b * CDIM * HH + h) * WW;

    for (int cc = 0; cc < 4; ++cc) {
        __syncthreads();
        for (int idx = tid; idx < 32 * DD * WW; idx += 1024) {
            const int ww = idx & 63;
            const int rest = idx >> 6;
            const int ki = rest % DD;
            const int cl = rest / DD;
            const int hp = reflect64(h + ki - RR);
            sS[cl][ki * WW + ww] = sb[(cc * 32 + cl) * HH * WW + hp * WW + ww];
        }
        __syncthreads();
        float acc[2] = {0.f, 0.f};
        for (int n = 0; n < DSQ; ++n) {
            const int ki = n / 7, kj = n % 7;
            const int off = ki * WW + reflect64(w + kj - RR);
            const float wv = sWts[n][w];
            #pragma unroll
            for (int j = 0; j < 2; ++j)
                acc[j] = fmaf(sS[q * 2 + j][off], wv, acc[j]);
        }
        #pragma unroll
        for (int j = 0; j < 2; ++j)
            orow[(cc * 32 + q * 2 + j) * HH * WW + w] = acc[j];
    }
}

extern "C" void kernel_launch(void* const* d_in, const int* in_sizes, int n_in,
                              void* d_out, int out_size, void* d_ws, size_t ws_size,
                              hipStream_t stream) {
    (void)in_sizes; (void)n_in; (void)out_size; (void)ws_size;
    const float* spatial  = (const float*)d_in[0];
    const float* semantic = (const float*)d_in[1];
    const float* rp_w1 = (const float*)d_in[2];
    const float* rp_b1 = (const float*)d_in[3];
    const float* rp_lnw = (const float*)d_in[4];
    const float* rp_lnb = (const float*)d_in[5];
    const float* rp_w2 = (const float*)d_in[6];
    const float* rp_b2 = (const float*)d_in[7];
    const float* fx_w1 = (const float*)d_in[8];
    const float* fx_b1 = (const float*)d_in[9];
    const float* fx_lnw = (const float*)d_in[10];
    const float* fx_lnb = (const float*)d_in[11];
    const float* fx_w2 = (const float*)d_in[12];
    const float* fx_b2 = (const float*)d_in[13];
    const float* sigma = (const float*)d_in[14];
    const float* op_w1 = (const float*)d_in[15];
    const float* op_b1 = (const float*)d_in[16];
    const float* op_lnw = (const float*)d_in[17];
    const float* op_lnb = (const float*)d_in[18];
    const float* op_w2 = (const float*)d_in[19];
    const float* op_b2 = (const float*)d_in[20];

    float* ws = (float*)d_ws;
    float* proj_x   = ws;                       // 2,097,152 floats
    float* combined = ws + 2097152;             //   802,816 floats
    float* wtsbuf   = ws + 2899968;             //   802,816 floats
    float* agg      = proj_x;                   // reuse (proj_x dead after simsoftmax)
    float* outp     = (float*)d_out;

    dim3 grid(BB * HH), blk(1024);
    proj_kernel<true><<<grid, blk, 0, stream>>>(semantic, rp_w1, rp_b1, rp_lnw, rp_lnb,
                                                rp_w2, rp_b2, proj_x);
    simsoftmax_kernel<<<grid, blk, 0, stream>>>(proj_x, sigma, combined);
    fixup_kernel<<<grid, blk, 0, stream>>>(combined, semantic, fx_w1, fx_b1, fx_lnw,
                                           fx_lnb, fx_w2, fx_b2, wtsbuf);
    aggregate_kernel<<<grid, blk, 0, stream>>>(spatial, wtsbuf, agg);
    proj_kernel<false><<<grid, blk, 0, stream>>>(agg, op_w1, op_b1, op_lnw, op_lnb,
                                                 op_w2, op_b2, outp);
}

// Round 7
// 146.072 us; speedup vs baseline: 1.6406x; 1.3381x over previous
//
#include <hip/hip_runtime.h>
#include <cstdint>

#define BB 4
#define CDIM 128
#define HH 64
#define WW 64
#define RR 3
#define DD 7
#define DSQ 49

__device__ __forceinline__ int reflect64(int p) {
    p = (p < 0) ? -p : p;
    return (p > 63) ? (126 - p) : p;
}
__device__ __forceinline__ float sigm(float x) { return 1.0f / (1.0f + __expf(-x)); }

// ---- conv1x1(128->128) -> LN(128) -> [SiLU] -> conv1x1(128->128), one (b,h) row per block
// 1024 threads = 16 waves; wave q owns 8 output channels. Weights via scalar loads.
template<bool SILU>
__global__ __launch_bounds__(1024) void proj_kernel(
    const float* __restrict__ x, const float* __restrict__ w1,
    const float* __restrict__ b1, const float* __restrict__ lnw,
    const float* __restrict__ lnb, const float* __restrict__ w2,
    const float* __restrict__ b2, float* __restrict__ out)
{
    __shared__ float sX[CDIM][WW];
    __shared__ float sY[CDIM][WW];
    __shared__ float red1[16][WW];
    __shared__ float red2[16][WW];

    const int tid = threadIdx.x;
    const int w = tid & 63;
    const int q = tid >> 6;        // 0..15, wave id
    const int qu = __builtin_amdgcn_readfirstlane(q);   // wave-uniform (scalar)
    const int b = blockIdx.x >> 6;
    const int h = blockIdx.x & 63;

    // float4 staging: 128 rows x 16 float4
    const float* xrow = x + (b * CDIM * HH + h) * WW;
    for (int idx = tid; idx < CDIM * 16; idx += 1024) {
        const int c = idx >> 4, pos = idx & 15;
        *reinterpret_cast<float4*>(&sX[c][pos * 4]) =
            *reinterpret_cast<const float4*>(&xrow[c * HH * WW + pos * 4]);
    }
    __syncthreads();

    float acc[8];
    #pragma unroll
    for (int k = 0; k < 8; ++k) acc[k] = b1[qu * 8 + k];
    #pragma unroll 2
    for (int i = 0; i < CDIM; i += 4) {
        float x0 = sX[i][w], x1 = sX[i+1][w], x2 = sX[i+2][w], x3 = sX[i+3][w];
        #pragma unroll
        for (int k = 0; k < 8; ++k) {
            const float4 wv = *reinterpret_cast<const float4*>(&w1[(qu*8+k)*CDIM + i]);
            acc[k] = fmaf(wv.x, x0, fmaf(wv.y, x1, fmaf(wv.z, x2, fmaf(wv.w, x3, acc[k]))));
        }
    }
    float s1 = 0.f, s2 = 0.f;
    #pragma unroll
    for (int k = 0; k < 8; ++k) { s1 += acc[k]; s2 += acc[k] * acc[k]; }
    red1[q][w] = s1; red2[q][w] = s2;
    __syncthreads();
    float t1 = 0.f, t2 = 0.f;
    #pragma unroll
    for (int j = 0; j < 16; ++j) { t1 += red1[j][w]; t2 += red2[j][w]; }
    const float mean = t1 * (1.0f / 128.0f);
    const float var  = t2 * (1.0f / 128.0f) - mean * mean;
    const float rstd = rsqrtf(var + 1e-6f);
    #pragma unroll
    for (int k = 0; k < 8; ++k) {
        const int o = qu * 8 + k;
        float v = (acc[k] - mean) * rstd * lnw[o] + lnb[o];
        if (SILU) v = v * sigm(v);
        sY[o][w] = v;
    }
    __syncthreads();
    float acc2[8];
    #pragma unroll
    for (int k = 0; k < 8; ++k) acc2[k] = b2[qu * 8 + k];
    #pragma unroll 2
    for (int i = 0; i < CDIM; i += 4) {
        float x0 = sY[i][w], x1 = sY[i+1][w], x2 = sY[i+2][w], x3 = sY[i+3][w];
        #pragma unroll
        for (int k = 0; k < 8; ++k) {
            const float4 wv = *reinterpret_cast<const float4*>(&w2[(qu*8+k)*CDIM + i]);
            acc2[k] = fmaf(wv.x, x0, fmaf(wv.y, x1, fmaf(wv.z, x2, fmaf(wv.w, x3, acc2[k]))));
        }
    }
    float* orow = out + (b * CDIM * HH + h) * WW;
    #pragma unroll
    for (int k = 0; k < 8; ++k)
        orow[(qu * 8 + k) * HH * WW + w] = acc2[k];
}

// ---- sim = <patch, center>/sqrt(C); softmax over 49; * gaussian spatial kernel
// 1024 threads; wave q handles n = q + 16*k, k<4. Float4 staging, unrolled channel loop.
__global__ __launch_bounds__(1024) void simsoftmax_kernel(
    const float* __restrict__ px, const float* __restrict__ sigma_p,
    float* __restrict__ combined)
{
    __shared__ float sP[32][DD * WW];   // 32-channel chunk, 7 reflected rows
    __shared__ float sSim[DSQ][WW];

    const int tid = threadIdx.x;
    const int w = tid & 63;
    const int q = tid >> 6;            // 0..15
    const int b = blockIdx.x >> 6;
    const int h = blockIdx.x & 63;

    int offk[4];
    #pragma unroll
    for (int k = 0; k < 4; ++k) {
        int n = q + 16 * k; if (n > 48) n = 48;   // clamp (garbage lanes never written back)
        const int ki = n / 7, kj = n % 7;
        offk[k] = ki * WW + reflect64(w + kj - RR);
    }

    float sim[4];
    #pragma unroll
    for (int k = 0; k < 4; ++k) sim[k] = 0.f;

    const float* pb = px + b * CDIM * HH * WW;
    for (int cc = 0; cc < 4; ++cc) {
        __syncthreads();
        // stage 32 ch x 7 rows x 16 float4 = 3584 f4
        for (int idx = tid; idx < 32 * DD * 16; idx += 1024) {
            const int pos = idx & 15;
            const int rk  = idx >> 4;          // cl*7 + ki
            const int cl  = rk / 7;
            const int ki  = rk - cl * 7;
            const int hp  = reflect64(h + ki - RR);
            *reinterpret_cast<float4*>(&sP[cl][ki * WW + pos * 4]) =
                *reinterpret_cast<const float4*>(
                    &pb[(cc * 32 + cl) * HH * WW + hp * WW + pos * 4]);
        }
        __syncthreads();
        #pragma unroll
        for (int cl = 0; cl < 32; ++cl) {
            const float xc = sP[cl][RR * WW + w];
            #pragma unroll
            for (int k = 0; k < 4; ++k)
                sim[k] = fmaf(sP[cl][offk[k]], xc, sim[k]);
        }
    }

    const float rscale = 0.088388347648318447f;  // 1/sqrt(128)
    #pragma unroll
    for (int k = 0; k < 4; ++k) {
        const int n = q + 16 * k;
        if (n < DSQ) sSim[n][w] = sim[k] * rscale;
    }
    __syncthreads();
    float m = -1e30f;
    #pragma unroll
    for (int n = 0; n < DSQ; ++n) m = fmaxf(m, sSim[n][w]);
    float ssum = 0.f;
    #pragma unroll
    for (int n = 0; n < DSQ; ++n) ssum += __expf(sSim[n][w] - m);
    const float inv = 1.0f / ssum;
    const float sigma = sigma_p[0];
    const float inv2s2 = 1.0f / (2.0f * sigma * sigma);
    float* cb = combined + (b * DSQ * HH + h) * WW;
    #pragma unroll
    for (int k = 0; k < 4; ++k) {
        const int n = q + 16 * k;
        if (n < DSQ) {
            const int ki = n / 7, kj = n % 7;
            const float dx = (float)(ki - 3) * (1.0f / 3.0f);
            const float dy = (float)(kj - 3) * (1.0f / 3.0f);
            const float sk = __expf(-(dx * dx + dy * dy) * inv2s2);
            cb[n * HH * WW + w] = __expf(sim[k] * rscale - m) * inv * sk;
        }
    }
}

// ---- fixup: conv(177->49) -> LN(49) -> SiLU -> conv(49->49) -> gate -> normalize
__global__ __launch_bounds__(1024) void fixup_kernel(
    const float* __restrict__ combined, const float* __restrict__ sem,
    const float* __restrict__ w1, const float* __restrict__ b1,
    const float* __restrict__ lnw, const float* __restrict__ lnb,
    const float* __restrict__ w2, const float* __restrict__ b2,
    float* __restrict__ wts)
{
    __shared__ float sCmb[DSQ][WW];
    __shared__ float sSem[CDIM][WW];
    __shared__ float sG[DSQ][WW];
    __shared__ float red1[16][WW];

    const int tid = threadIdx.x;
    const int w = tid & 63;
    const int q = tid >> 6;            // 0..15
    const int qu = __builtin_amdgcn_readfirstlane(q);
    const int b = blockIdx.x >> 6;
    const int h = blockIdx.x & 63;

    const float* crow = combined + (b * DSQ * HH + h) * WW;
    for (int idx = tid; idx < DSQ * 16; idx += 1024) {
        const int r = idx >> 4, pos = idx & 15;
        *reinterpret_cast<float4*>(&sCmb[r][pos * 4]) =
            *reinterpret_cast<const float4*>(&crow[r * HH * WW + pos * 4]);
    }
    const float* srow = sem + (b * CDIM * HH + h) * WW;
    for (int idx = tid; idx < CDIM * 16; idx += 1024) {
        const int r = idx >> 4, pos = idx & 15;
        *reinterpret_cast<float4*>(&sSem[r][pos * 4]) =
            *reinterpret_cast<const float4*>(&srow[r * HH * WW + pos * 4]);
    }
    __syncthreads();

    int ok[4];
    #pragma unroll
    for (int k = 0; k < 4; ++k) {
        int o = qu + 16 * k; if (o > 48) o = 48;   // scalar clamp
        ok[k] = o;
    }

    float g[4];
    #pragma unroll
    for (int k = 0; k < 4; ++k) g[k] = b1[ok[k]];
    #pragma unroll 4
    for (int i = 0; i < DSQ; ++i) {
        const float xv = sCmb[i][w];
        #pragma unroll
        for (int k = 0; k < 4; ++k)
            g[k] = fmaf(w1[ok[k] * 177 + i], xv, g[k]);
    }
    #pragma unroll 4
    for (int c = 0; c < CDIM; ++c) {
        const float xv = sSem[c][w];
        #pragma unroll
        for (int k = 0; k < 4; ++k)
            g[k] = fmaf(w1[ok[k] * 177 + DSQ + c], xv, g[k]);
    }
    float s1 = 0.f, s2 = 0.f;
    #pragma unroll
    for (int k = 0; k < 4; ++k)
        if (q + 16 * k < DSQ) { s1 += g[k]; s2 += g[k] * g[k]; }
    red1[q][w] = s1;
    __syncthreads();
    float t1 = 0.f;
    #pragma unroll
    for (int j = 0; j < 16; ++j) t1 += red1[j][w];
    __syncthreads();
    red1[q][w] = s2;
    __syncthreads();
    float t2 = 0.f;
    #pragma unroll
    for (int j = 0; j < 16; ++j) t2 += red1[j][w];
    const float mean = t1 * (1.0f / 49.0f);
    const float var  = t2 * (1.0f / 49.0f) - mean * mean;
    const float rstd = rsqrtf(var + 1e-6f);
    #pragma unroll
    for (int k = 0; k < 4; ++k) {
        const int o = q + 16 * k;
        if (o < DSQ) {
            float v = (g[k] - mean) * rstd * lnw[ok[k]] + lnb[ok[k]];
            sG[o][w] = v * sigm(v);
        }
    }
    __syncthreads();
    float f[4];
    #pragma unroll
    for (int k = 0; k < 4; ++k) f[k] = b2[ok[k]];
    #pragma unroll 4
    for (int i = 0; i < DSQ; ++i) {
        const float xv = sG[i][w];
        #pragma unroll
        for (int k = 0; k < 4; ++k)
            f[k] = fmaf(w2[ok[k] * DSQ + i], xv, f[k]);
    }
    float c2[4];
    float ps = 0.f;
    #pragma unroll
    for (int k = 0; k < 4; ++k) {
        const int o = q + 16 * k;
        if (o < DSQ) {
            c2[k] = sCmb[o][w] * (1.0f + sigm(f[k]));
            ps += c2[k];
        } else c2[k] = 0.f;
    }
    __syncthreads();
    red1[q][w] = ps;
    __syncthreads();
    float tot = 0.f;
    #pragma unroll
    for (int j = 0; j < 16; ++j) tot += red1[j][w];
    const float invt = 1.0f / (tot + 1e-7f);
    float* wrow = wts + (b * DSQ * HH + h) * WW;
    #pragma unroll
    for (int k = 0; k < 4; ++k) {
        const int o = q + 16 * k;
        if (o < DSQ) wrow[o * HH * WW + w] = c2[k] * invt;
    }
}

// ---- out0[c] = sum_n spatial[c, nbr(n)] * wts[n]
// wts preloaded to 49 registers; n-loop fully unrolled; float4 staging.
__global__ __launch_bounds__(1024) void aggregate_kernel(
    const float* __restrict__ spatial, const float* __restrict__ wts,
    float* __restrict__ out)
{
    __shared__ float sS[32][DD * WW];   // 57344 B

    const int tid = threadIdx.x;
    const int w = tid & 63;
    const int q = tid >> 6;            // 0..15
    const int b = blockIdx.x >> 6;
    const int h = blockIdx.x & 63;

    // preload all 49 pixel weights into registers (static indexing via unroll)
    float wv[DSQ];
    {
        const float* wrow = wts + (b * DSQ * HH + h) * WW + w;
        #pragma unroll
        for (int n = 0; n < DSQ; ++n) wv[n] = wrow[n * HH * WW];
    }
    // 7 reflected column offsets
    int coff[DD];
    #pragma unroll
    for (int kj = 0; kj < DD; ++kj) coff[kj] = reflect64(w + kj - RR);

    const float* sb = spatial + b * CDIM * HH * WW;
    float* orow = out + (b * CDIM * HH + h) * WW;
    const int c0 = q * 2;

    for (int cc = 0; cc < 4; ++cc) {
        __syncthreads();
        // stage 32 ch x 7 rows x 16 float4
        for (int idx = tid; idx < 32 * DD * 16; idx += 1024) {
            const int pos = idx & 15;
            const int rk  = idx >> 4;          // cl*7 + ki
            const int cl  = rk / 7;
            const int ki  = rk - cl * 7;
            const int hp  = reflect64(h + ki - RR);
            *reinterpret_cast<float4*>(&sS[cl][ki * WW + pos * 4]) =
                *reinterpret_cast<const float4*>(
                    &sb[(cc * 32 + cl) * HH * WW + hp * WW + pos * 4]);
        }
        __syncthreads();
        float acc0 = 0.f, acc1 = 0.f;
        #pragma unroll
        for (int n = 0; n < DSQ; ++n) {
            const int ki = n / 7, kj = n % 7;       // compile-time
            const int off = ki * WW + coff[kj];
            acc0 = fmaf(sS[c0][off],     wv[n], acc0);
            acc1 = fmaf(sS[c0 + 1][off], wv[n], acc1);
        }
        orow[(cc * 32 + c0) * HH * WW + w]     = acc0;
        orow[(cc * 32 + c0 + 1) * HH * WW + w] = acc1;
    }
}

extern "C" void kernel_launch(void* const* d_in, const int* in_sizes, int n_in,
                              void* d_out, int out_size, void* d_ws, size_t ws_size,
                              hipStream_t stream) {
    (void)in_sizes; (void)n_in; (void)out_size; (void)ws_size;
    const float* spatial  = (const float*)d_in[0];
    const float* semantic = (const float*)d_in[1];
    const float* rp_w1 = (const float*)d_in[2];
    const float* rp_b1 = (const float*)d_in[3];
    const float* rp_lnw = (const float*)d_in[4];
    const float* rp_lnb = (const float*)d_in[5];
    const float* rp_w2 = (const float*)d_in[6];
    const float* rp_b2 = (const float*)d_in[7];
    const float* fx_w1 = (const float*)d_in[8];
    const float* fx_b1 = (const float*)d_in[9];
    const float* fx_lnw = (const float*)d_in[10];
    const float* fx_lnb = (const float*)d_in[11];
    const float* fx_w2 = (const float*)d_in[12];
    const float* fx_b2 = (const float*)d_in[13];
    const float* sigma = (const float*)d_in[14];
    const float* op_w1 = (const float*)d_in[15];
    const float* op_b1 = (const float*)d_in[16];
    const float* op_lnw = (const float*)d_in[17];
    const float* op_lnb = (const float*)d_in[18];
    const float* op_w2 = (const float*)d_in[19];
    const float* op_b2 = (const float*)d_in[20];

    float* ws = (float*)d_ws;
    float* proj_x   = ws;                       // 2,097,152 floats
    float* combined = ws + 2097152;             //   802,816 floats
    float* wtsbuf   = ws + 2899968;             //   802,816 floats
    float* agg      = proj_x;                   // reuse (proj_x dead after simsoftmax)
    float* outp     = (float*)d_out;

    dim3 grid(BB * HH), blk(1024);
    proj_kernel<true><<<grid, blk, 0, stream>>>(semantic, rp_w1, rp_b1, rp_lnw, rp_lnb,
                                                rp_w2, rp_b2, proj_x);
    simsoftmax_kernel<<<grid, blk, 0, stream>>>(proj_x, sigma, combined);
    fixup_kernel<<<grid, blk, 0, stream>>>(combined, semantic, fx_w1, fx_b1, fx_lnw,
                                           fx_lnb, fx_w2, fx_b2, wtsbuf);
    aggregate_kernel<<<grid, blk, 0, stream>>>(spatial, wtsbuf, agg);
    proj_kernel<false><<<grid, blk, 0, stream>>>(agg, op_w1, op_b1, op_lnw, op_lnb,
                                                 op_w2, op_b2, outp);
}

// Round 8
// 125.802 us; speedup vs baseline: 1.9049x; 1.1611x over previous
//
#include <hip/hip_runtime.h>
#include <cstdint>

#define BB 4
#define CDIM 128
#define HH 64
#define WW 64
#define RR 3
#define DD 7
#define DSQ 49

__device__ __forceinline__ int reflect64(int p) {
    p = (p < 0) ? -p : p;
    return (p > 63) ? (126 - p) : p;
}
__device__ __forceinline__ float sigm(float x) { return 1.0f / (1.0f + __expf(-x)); }

// ---- conv1x1(128->128) -> LN(128) -> [SiLU] -> conv1x1(128->128), one (b,h) row per block
// 16 waves; wave q owns 8 contiguous output channels. Weights staged in LDS (w1, then w2
// reusing the same buffer) and read via uniform ds_read_b128 broadcast -> no SMEM/DS
// lgkmcnt mixing in the inner loop.
template<bool SILU>
__global__ __launch_bounds__(1024) void proj_kernel(
    const float* __restrict__ x, const float* __restrict__ w1,
    const float* __restrict__ b1, const float* __restrict__ lnw,
    const float* __restrict__ lnb, const float* __restrict__ w2,
    const float* __restrict__ b2, float* __restrict__ out)
{
    __shared__ alignas(16) float sW[CDIM][CDIM];   // 64 KB, holds w1 then w2
    __shared__ alignas(16) float sX[CDIM][WW];
    __shared__ alignas(16) float sY[CDIM][WW];
    __shared__ float red1[16][WW];
    __shared__ float red2[16][WW];

    const int tid = threadIdx.x;
    const int w = tid & 63;
    const int q = tid >> 6;        // 0..15
    const int qu = __builtin_amdgcn_readfirstlane(q);
    const int b = blockIdx.x >> 6;
    const int h = blockIdx.x & 63;

    // stage x row (float4) and w1 (float4)
    const float* xrow = x + (b * CDIM * HH + h) * WW;
    for (int idx = tid; idx < CDIM * 16; idx += 1024) {
        const int c = idx >> 4, pos = idx & 15;
        *reinterpret_cast<float4*>(&sX[c][pos * 4]) =
            *reinterpret_cast<const float4*>(&xrow[c * HH * WW + pos * 4]);
    }
    for (int idx = tid; idx < CDIM * 32; idx += 1024) {
        const int r = idx >> 5, p = idx & 31;
        *reinterpret_cast<float4*>(&sW[r][p * 4]) =
            *reinterpret_cast<const float4*>(&w1[r * CDIM + p * 4]);
    }
    __syncthreads();

    float acc[8];
    #pragma unroll
    for (int k = 0; k < 8; ++k) acc[k] = b1[qu * 8 + k];
    #pragma unroll 2
    for (int i = 0; i < CDIM; i += 4) {
        const float x0 = sX[i][w], x1 = sX[i+1][w], x2 = sX[i+2][w], x3 = sX[i+3][w];
        #pragma unroll
        for (int k = 0; k < 8; ++k) {
            const float4 wv = *reinterpret_cast<const float4*>(&sW[qu * 8 + k][i]);
            acc[k] = fmaf(wv.x, x0, fmaf(wv.y, x1, fmaf(wv.z, x2, fmaf(wv.w, x3, acc[k]))));
        }
    }
    float s1 = 0.f, s2 = 0.f;
    #pragma unroll
    for (int k = 0; k < 8; ++k) { s1 += acc[k]; s2 += acc[k] * acc[k]; }
    red1[q][w] = s1; red2[q][w] = s2;
    __syncthreads();
    float t1 = 0.f, t2 = 0.f;
    #pragma unroll
    for (int j = 0; j < 16; ++j) { t1 += red1[j][w]; t2 += red2[j][w]; }
    const float mean = t1 * (1.0f / 128.0f);
    const float var  = t2 * (1.0f / 128.0f) - mean * mean;
    const float rstd = rsqrtf(var + 1e-6f);
    #pragma unroll
    for (int k = 0; k < 8; ++k) {
        const int o = qu * 8 + k;
        float v = (acc[k] - mean) * rstd * lnw[o] + lnb[o];
        if (SILU) v = v * sigm(v);
        sY[o][w] = v;
    }
    __syncthreads();                 // sY ready; all conv1 sW reads long done
    // stage w2 over sW
    for (int idx = tid; idx < CDIM * 32; idx += 1024) {
        const int r = idx >> 5, p = idx & 31;
        *reinterpret_cast<float4*>(&sW[r][p * 4]) =
            *reinterpret_cast<const float4*>(&w2[r * CDIM + p * 4]);
    }
    __syncthreads();

    float acc2[8];
    #pragma unroll
    for (int k = 0; k < 8; ++k) acc2[k] = b2[qu * 8 + k];
    #pragma unroll 2
    for (int i = 0; i < CDIM; i += 4) {
        const float x0 = sY[i][w], x1 = sY[i+1][w], x2 = sY[i+2][w], x3 = sY[i+3][w];
        #pragma unroll
        for (int k = 0; k < 8; ++k) {
            const float4 wv = *reinterpret_cast<const float4*>(&sW[qu * 8 + k][i]);
            acc2[k] = fmaf(wv.x, x0, fmaf(wv.y, x1, fmaf(wv.z, x2, fmaf(wv.w, x3, acc2[k]))));
        }
    }
    float* orow = out + (b * CDIM * HH + h) * WW;
    #pragma unroll
    for (int k = 0; k < 8; ++k)
        orow[(qu * 8 + k) * HH * WW + w] = acc2[k];
}

// ---- sim = <patch, center>/sqrt(C); softmax over 49; * gaussian spatial kernel
__global__ __launch_bounds__(1024) void simsoftmax_kernel(
    const float* __restrict__ px, const float* __restrict__ sigma_p,
    float* __restrict__ combined)
{
    __shared__ alignas(16) float sP[32][DD * WW];
    __shared__ float sSim[DSQ][WW];

    const int tid = threadIdx.x;
    const int w = tid & 63;
    const int q = tid >> 6;            // 0..15
    const int b = blockIdx.x >> 6;
    const int h = blockIdx.x & 63;

    int offk[4];
    #pragma unroll
    for (int k = 0; k < 4; ++k) {
        int n = q + 16 * k; if (n > 48) n = 48;
        const int ki = n / 7, kj = n % 7;
        offk[k] = ki * WW + reflect64(w + kj - RR);
    }

    float sim[4];
    #pragma unroll
    for (int k = 0; k < 4; ++k) sim[k] = 0.f;

    const float* pb = px + b * CDIM * HH * WW;
    for (int cc = 0; cc < 4; ++cc) {
        __syncthreads();
        for (int idx = tid; idx < 32 * DD * 16; idx += 1024) {
            const int pos = idx & 15;
            const int rk  = idx >> 4;
            const int cl  = rk / 7;
            const int ki  = rk - cl * 7;
            const int hp  = reflect64(h + ki - RR);
            *reinterpret_cast<float4*>(&sP[cl][ki * WW + pos * 4]) =
                *reinterpret_cast<const float4*>(
                    &pb[(cc * 32 + cl) * HH * WW + hp * WW + pos * 4]);
        }
        __syncthreads();
        #pragma unroll
        for (int cl = 0; cl < 32; ++cl) {
            const float xc = sP[cl][RR * WW + w];
            #pragma unroll
            for (int k = 0; k < 4; ++k)
                sim[k] = fmaf(sP[cl][offk[k]], xc, sim[k]);
        }
    }

    const float rscale = 0.088388347648318447f;  // 1/sqrt(128)
    #pragma unroll
    for (int k = 0; k < 4; ++k) {
        const int n = q + 16 * k;
        if (n < DSQ) sSim[n][w] = sim[k] * rscale;
    }
    __syncthreads();
    float m = -1e30f;
    #pragma unroll
    for (int n = 0; n < DSQ; ++n) m = fmaxf(m, sSim[n][w]);
    float ssum = 0.f;
    #pragma unroll
    for (int n = 0; n < DSQ; ++n) ssum += __expf(sSim[n][w] - m);
    const float inv = 1.0f / ssum;
    const float sigma = sigma_p[0];
    const float inv2s2 = 1.0f / (2.0f * sigma * sigma);
    float* cb = combined + (b * DSQ * HH + h) * WW;
    #pragma unroll
    for (int k = 0; k < 4; ++k) {
        const int n = q + 16 * k;
        if (n < DSQ) {
            const int ki = n / 7, kj = n % 7;
            const float dx = (float)(ki - 3) * (1.0f / 3.0f);
            const float dy = (float)(kj - 3) * (1.0f / 3.0f);
            const float sk = __expf(-(dx * dx + dy * dy) * inv2s2);
            cb[n * HH * WW + w] = __expf(sim[k] * rscale - m) * inv * sk;
        }
    }
}

// ---- fixup: conv(177->49) -> LN(49) -> SiLU -> conv(49->49) -> gate -> normalize
// All weights staged in LDS (zero-padded rows/cols so step-4 loops have no tails);
// uniform ds_read_b128 weight reads, DS-only inner loops.
__global__ __launch_bounds__(1024) void fixup_kernel(
    const float* __restrict__ combined, const float* __restrict__ sem,
    const float* __restrict__ w1, const float* __restrict__ b1,
    const float* __restrict__ lnw, const float* __restrict__ lnb,
    const float* __restrict__ w2, const float* __restrict__ b2,
    float* __restrict__ wts)
{
    __shared__ alignas(16) float sCmb[52][WW];      // rows 49..51 zero
    __shared__ alignas(16) float sSem[CDIM][WW];
    __shared__ alignas(16) float sG[52][WW];        // rows 49..51 zero
    __shared__ alignas(16) float sW1a[DSQ][52];     // w1[:, 0:49], cols 49..51 zero
    __shared__ alignas(16) float sW1b[DSQ][CDIM];   // w1[:, 49:177]
    __shared__ alignas(16) float sW2[DSQ][52];      // w2, cols 49..51 zero
    __shared__ float red1[16][WW];
    __shared__ float red2[16][WW];

    const int tid = threadIdx.x;
    const int w = tid & 63;
    const int q = tid >> 6;            // 0..15
    const int qu = __builtin_amdgcn_readfirstlane(q);
    const int b = blockIdx.x >> 6;
    const int h = blockIdx.x & 63;

    // ---- staging ----
    const float* crow = combined + (b * DSQ * HH + h) * WW;
    for (int idx = tid; idx < 52 * 16; idx += 1024) {
        const int r = idx >> 4, pos = idx & 15;
        float4 v = make_float4(0.f, 0.f, 0.f, 0.f);
        if (r < DSQ) v = *reinterpret_cast<const float4*>(&crow[r * HH * WW + pos * 4]);
        *reinterpret_cast<float4*>(&sCmb[r][pos * 4]) = v;
    }
    const float* srow = sem + (b * CDIM * HH + h) * WW;
    for (int idx = tid; idx < CDIM * 16; idx += 1024) {
        const int r = idx >> 4, pos = idx & 15;
        *reinterpret_cast<float4*>(&sSem[r][pos * 4]) =
            *reinterpret_cast<const float4*>(&srow[r * HH * WW + pos * 4]);
    }
    for (int idx = tid; idx < DSQ * 52; idx += 1024) {      // 2548
        const int r = idx / 52, c = idx - r * 52;
        sW1a[r][c] = (c < DSQ) ? w1[r * 177 + c] : 0.f;
        sW2[r][c]  = (c < DSQ) ? w2[r * DSQ + c] : 0.f;
    }
    for (int idx = tid; idx < DSQ * CDIM; idx += 1024) {    // 6272
        const int r = idx >> 7, c = idx & 127;
        sW1b[r][c] = w1[r * 177 + DSQ + c];
    }
    if (tid < 3 * 64) sG[DSQ + (tid >> 6)][tid & 63] = 0.f; // zero pad rows of sG
    __syncthreads();

    int ok[4];
    #pragma unroll
    for (int k = 0; k < 4; ++k) {
        int o = qu + 16 * k; if (o > 48) o = 48;   // scalar clamp (dup compute, not stored)
        ok[k] = o;
    }

    // ---- conv1: 177 -> 49 ----
    float g[4];
    #pragma unroll
    for (int k = 0; k < 4; ++k) g[k] = b1[ok[k]];
    #pragma unroll 2
    for (int i = 0; i < 52; i += 4) {
        const float x0 = sCmb[i][w], x1 = sCmb[i+1][w], x2 = sCmb[i+2][w], x3 = sCmb[i+3][w];
        #pragma unroll
        for (int k = 0; k < 4; ++k) {
            const float4 wv = *reinterpret_cast<const float4*>(&sW1a[ok[k]][i]);
            g[k] = fmaf(wv.x, x0, fmaf(wv.y, x1, fmaf(wv.z, x2, fmaf(wv.w, x3, g[k]))));
        }
    }
    #pragma unroll 2
    for (int c = 0; c < CDIM; c += 4) {
        const float x0 = sSem[c][w], x1 = sSem[c+1][w], x2 = sSem[c+2][w], x3 = sSem[c+3][w];
        #pragma unroll
        for (int k = 0; k < 4; ++k) {
            const float4 wv = *reinterpret_cast<const float4*>(&sW1b[ok[k]][c]);
            g[k] = fmaf(wv.x, x0, fmaf(wv.y, x1, fmaf(wv.z, x2, fmaf(wv.w, x3, g[k]))));
        }
    }
    // ---- LN(49) ----
    float s1 = 0.f, s2 = 0.f;
    #pragma unroll
    for (int k = 0; k < 4; ++k)
        if (q + 16 * k < DSQ) { s1 += g[k]; s2 += g[k] * g[k]; }
    red1[q][w] = s1; red2[q][w] = s2;
    __syncthreads();
    float t1 = 0.f, t2 = 0.f;
    #pragma unroll
    for (int j = 0; j < 16; ++j) { t1 += red1[j][w]; t2 += red2[j][w]; }
    const float mean = t1 * (1.0f / 49.0f);
    const float var  = t2 * (1.0f / 49.0f) - mean * mean;
    const float rstd = rsqrtf(var + 1e-6f);
    #pragma unroll
    for (int k = 0; k < 4; ++k) {
        const int o = q + 16 * k;
        if (o < DSQ) {
            float v = (g[k] - mean) * rstd * lnw[ok[k]] + lnb[ok[k]];
            sG[o][w] = v * sigm(v);
        }
    }
    __syncthreads();
    // ---- conv2: 49 -> 49 ----
    float f[4];
    #pragma unroll
    for (int k = 0; k < 4; ++k) f[k] = b2[ok[k]];
    #pragma unroll 2
    for (int i = 0; i < 52; i += 4) {
        const float x0 = sG[i][w], x1 = sG[i+1][w], x2 = sG[i+2][w], x3 = sG[i+3][w];
        #pragma unroll
        for (int k = 0; k < 4; ++k) {
            const float4 wv = *reinterpret_cast<const float4*>(&sW2[ok[k]][i]);
            f[k] = fmaf(wv.x, x0, fmaf(wv.y, x1, fmaf(wv.z, x2, fmaf(wv.w, x3, f[k]))));
        }
    }
    // ---- gate + normalize ----
    float c2[4];
    float ps = 0.f;
    #pragma unroll
    for (int k = 0; k < 4; ++k) {
        const int o = q + 16 * k;
        if (o < DSQ) {
            c2[k] = sCmb[o][w] * (1.0f + sigm(f[k]));
            ps += c2[k];
        } else c2[k] = 0.f;
    }
    red1[q][w] = ps;
    __syncthreads();
    float tot = 0.f;
    #pragma unroll
    for (int j = 0; j < 16; ++j) tot += red1[j][w];
    const float invt = 1.0f / (tot + 1e-7f);
    float* wrow = wts + (b * DSQ * HH + h) * WW;
    #pragma unroll
    for (int k = 0; k < 4; ++k) {
        const int o = q + 16 * k;
        if (o < DSQ) wrow[o * HH * WW + w] = c2[k] * invt;
    }
}

// ---- out0[c] = sum_n spatial[c, nbr(n)] * wts[n]
__global__ __launch_bounds__(1024) void aggregate_kernel(
    const float* __restrict__ spatial, const float* __restrict__ wts,
    float* __restrict__ out)
{
    __shared__ alignas(16) float sS[32][DD * WW];

    const int tid = threadIdx.x;
    const int w = tid & 63;
    const int q = tid >> 6;
    const int b = blockIdx.x >> 6;
    const int h = blockIdx.x & 63;

    float wv[DSQ];
    {
        const float* wrow = wts + (b * DSQ * HH + h) * WW + w;
        #pragma unroll
        for (int n = 0; n < DSQ; ++n) wv[n] = wrow[n * HH * WW];
    }
    int coff[DD];
    #pragma unroll
    for (int kj = 0; kj < DD; ++kj) coff[kj] = reflect64(w + kj - RR);

    const float* sb = spatial + b * CDIM * HH * WW;
    float* orow = out + (b * CDIM * HH + h) * WW;
    const int c0 = q * 2;

    for (int cc = 0; cc < 4; ++cc) {
        __syncthreads();
        for (int idx = tid; idx < 32 * DD * 16; idx += 1024) {
            const int pos = idx & 15;
            const int rk  = idx >> 4;
            const int cl  = rk / 7;
            const int ki  = rk - cl * 7;
            const int hp  = reflect64(h + ki - RR);
            *reinterpret_cast<float4*>(&sS[cl][ki * WW + pos * 4]) =
                *reinterpret_cast<const float4*>(
                    &sb[(cc * 32 + cl) * HH * WW + hp * WW + pos * 4]);
        }
        __syncthreads();
        float acc0 = 0.f, acc1 = 0.f;
        #pragma unroll
        for (int n = 0; n < DSQ; ++n) {
            const int ki = n / 7, kj = n % 7;       // compile-time
            const int off = ki * WW + coff[kj];
            acc0 = fmaf(sS[c0][off],     wv[n], acc0);
            acc1 = fmaf(sS[c0 + 1][off], wv[n], acc1);
        }
        orow[(cc * 32 + c0) * HH * WW + w]     = acc0;
        orow[(cc * 32 + c0 + 1) * HH * WW + w] = acc1;
    }
}

extern "C" void kernel_launch(void* const* d_in, const int* in_sizes, int n_in,
                              void* d_out, int out_size, void* d_ws, size_t ws_size,
                              hipStream_t stream) {
    (void)in_sizes; (void)n_in; (void)out_size; (void)ws_size;
    const float* spatial  = (const float*)d_in[0];
    const float* semantic = (const float*)d_in[1];
    const float* rp_w1 = (const float*)d_in[2];
    const float* rp_b1 = (const float*)d_in[3];
    const float* rp_lnw = (const float*)d_in[4];
    const float* rp_lnb = (const float*)d_in[5];
    const float* rp_w2 = (const float*)d_in[6];
    const float* rp_b2 = (const float*)d_in[7];
    const float* fx_w1 = (const float*)d_in[8];
    const float* fx_b1 = (const float*)d_in[9];
    const float* fx_lnw = (const float*)d_in[10];
    const float* fx_lnb = (const float*)d_in[11];
    const float* fx_w2 = (const float*)d_in[12];
    const float* fx_b2 = (const float*)d_in[13];
    const float* sigma = (const float*)d_in[14];
    const float* op_w1 = (const float*)d_in[15];
    const float* op_b1 = (const float*)d_in[16];
    const float* op_lnw = (const float*)d_in[17];
    const float* op_lnb = (const float*)d_in[18];
    const float* op_w2 = (const float*)d_in[19];
    const float* op_b2 = (const float*)d_in[20];

    float* ws = (float*)d_ws;
    float* proj_x   = ws;                       // 2,097,152 floats
    float* combined = ws + 2097152;             //   802,816 floats
    float* wtsbuf   = ws + 2899968;             //   802,816 floats
    float* agg      = proj_x;                   // reuse (proj_x dead after simsoftmax)
    float* outp     = (float*)d_out;

    dim3 grid(BB * HH), blk(1024);
    proj_kernel<true><<<grid, blk, 0, stream>>>(semantic, rp_w1, rp_b1, rp_lnw, rp_lnb,
                                                rp_w2, rp_b2, proj_x);
    simsoftmax_kernel<<<grid, blk, 0, stream>>>(proj_x, sigma, combined);
    fixup_kernel<<<grid, blk, 0, stream>>>(combined, semantic, fx_w1, fx_b1, fx_lnw,
                                           fx_lnb, fx_w2, fx_b2, wtsbuf);
    aggregate_kernel<<<grid, blk, 0, stream>>>(spatial, wtsbuf, agg);
    proj_kernel<false><<<grid, blk, 0, stream>>>(agg, op_w1, op_b1, op_lnw, op_lnb,
                                                 op_w2, op_b2, outp);
}

// Round 9
// 83.980 us; speedup vs baseline: 2.8536x; 1.4980x over previous
//
#include <hip/hip_runtime.h>
#include <cstdint>

#define BB 4
#define CDIM 128
#define HH 64
#define WW 64
#define RR 3
#define DD 7
#define DSQ 49

typedef __attribute__((ext_vector_type(8))) short short8v;   // 8 bf16 = 4 VGPR
typedef __attribute__((ext_vector_type(4))) float float4v;

__device__ __forceinline__ int reflect64(int p) {
    p = (p < 0) ? -p : p;
    return (p > 63) ? (126 - p) : p;
}
__device__ __forceinline__ float sigm(float x) { return 1.0f / (1.0f + __expf(-x)); }
__device__ __forceinline__ short f2bf(float f) {     // f32 -> bf16 RNE
    uint32_t u = __float_as_uint(f);
    u += 0x7FFF + ((u >> 16) & 1);
    return (short)(u >> 16);
}

// ---- conv1x1(128->128) -> LN(128) -> [SiLU] -> conv1x1(128->128) via bf16 MFMA.
// One (b,h) row per block = 128x64x128 GEMM x2. 16 waves, 2 16x16 tiles each.
// LDS layouts: W bf16 [o][i] swizzled idx = o*128 + (i ^ ((o&7)<<3)); X^T bf16 [p][i] same.
template<bool SILU>
__global__ __launch_bounds__(1024) void proj_kernel(
    const float* __restrict__ x, const float* __restrict__ w1,
    const float* __restrict__ b1, const float* __restrict__ lnw,
    const float* __restrict__ lnb, const float* __restrict__ w2,
    const float* __restrict__ b2, float* __restrict__ out)
{
    __shared__ short sW1[CDIM * CDIM];   // 32 KB
    __shared__ short sW2[CDIM * CDIM];   // 32 KB
    __shared__ short sXT[WW * CDIM];     // 16 KB  (conv1 B operand, [p][i])
    __shared__ short sXT2[WW * CDIM];    // 16 KB  (conv2 B operand)
    __shared__ float sT[CDIM][65];       // 33 KB  conv1 raw out (padded)
    __shared__ float red1[16][WW];
    __shared__ float red2[16][WW];

    const int tid = threadIdx.x;
    const int l = tid & 63;
    const int q = tid >> 6;                                 // wave 0..15
    const int qu = __builtin_amdgcn_readfirstlane(q);
    const int b = blockIdx.x >> 6;
    const int h = blockIdx.x & 63;

    // ---- stage W1, W2 as bf16 swizzled (thread t: row o=t>>3, 16 cols from (t&7)*16) ----
    {
        const int o = tid >> 3;
        const int i0 = (tid & 7) * 16;
        const int sw = (o & 7) << 3;
        const float* wsrc[2] = {w1, w2};
        short* wdst[2] = {sW1, sW2};
        #pragma unroll
        for (int m = 0; m < 2; ++m) {
            const float* src = wsrc[m] + o * CDIM + i0;
            short8v pk0, pk1;
            #pragma unroll
            for (int j = 0; j < 8; ++j) pk0[j] = f2bf(src[j]);
            #pragma unroll
            for (int j = 0; j < 8; ++j) pk1[j] = f2bf(src[8 + j]);
            *reinterpret_cast<short8v*>(&wdst[m][o * 128 + (i0 ^ sw)]) = pk0;
            *reinterpret_cast<short8v*>(&wdst[m][o * 128 + ((i0 + 8) ^ sw)]) = pk1;
        }
    }
    // ---- stage X^T bf16 swizzled ----
    {
        const int pos = tid & 15;          // px group
        const int c0 = tid >> 4;           // 0..63
        const float* xrow = x + (b * CDIM * HH + h) * WW;
        #pragma unroll
        for (int rr = 0; rr < 2; ++rr) {
            const int c = c0 + rr * 64;
            const float4 v = *reinterpret_cast<const float4*>(&xrow[c * HH * WW + pos * 4]);
            #pragma unroll
            for (int m = 0; m < 4; ++m) {
                const int p = pos * 4 + m;
                sXT[p * 128 + (c ^ ((p & 7) << 3))] = f2bf(((const float*)&v)[m]);
            }
        }
    }
    __syncthreads();

    const int lm = l & 15, g = l >> 4;
    const int tm = q >> 1;                 // M-tile 0..7
    const int tn0 = (q & 1) * 2;           // N-tiles tn0, tn0+1

    const int oa = tm * 16 + lm;           // A row this lane reads
    const int arow = oa * 128, asw = (oa & 7) << 3;
    const int p0 = tn0 * 16 + lm, p1 = (tn0 + 1) * 16 + lm;
    const int bsw0 = (p0 & 7) << 3, bsw1 = (p1 & 7) << 3;

    // ---- conv1 MFMA ----
    float4v acc0 = {0.f, 0.f, 0.f, 0.f}, acc1 = {0.f, 0.f, 0.f, 0.f};
    #pragma unroll
    for (int kk = 0; kk < 4; ++kk) {
        const int ki = kk * 32 + g * 8;
        const short8v af = *reinterpret_cast<const short8v*>(&sW1[arow + (ki ^ asw)]);
        const short8v bf0 = *reinterpret_cast<const short8v*>(&sXT[p0 * 128 + (ki ^ bsw0)]);
        const short8v bf1 = *reinterpret_cast<const short8v*>(&sXT[p1 * 128 + (ki ^ bsw1)]);
        acc0 = __builtin_amdgcn_mfma_f32_16x16x32_bf16(af, bf0, acc0, 0, 0, 0);
        acc1 = __builtin_amdgcn_mfma_f32_16x16x32_bf16(af, bf1, acc1, 0, 0, 0);
    }
    // D: col = lane&15, row = 4*(lane>>4)+r
    #pragma unroll
    for (int r = 0; r < 4; ++r) sT[tm * 16 + g * 4 + r][p0] = acc0[r];
    #pragma unroll
    for (int r = 0; r < 4; ++r) sT[tm * 16 + g * 4 + r][p1] = acc1[r];
    __syncthreads();

    // ---- bias + LN(128) + SiLU -> sXT2 bf16 ----
    {
        const int p = l;
        float vals[8];
        float s1 = 0.f, s2 = 0.f;
        #pragma unroll
        for (int j = 0; j < 8; ++j) {
            const float v = sT[qu * 8 + j][p] + b1[qu * 8 + j];
            vals[j] = v; s1 += v; s2 += v * v;
        }
        red1[q][p] = s1; red2[q][p] = s2;
        __syncthreads();
        float t1 = 0.f, t2 = 0.f;
        #pragma unroll
        for (int j = 0; j < 16; ++j) { t1 += red1[j][p]; t2 += red2[j][p]; }
        const float mean = t1 * (1.0f / 128.0f);
        const float var  = t2 * (1.0f / 128.0f) - mean * mean;
        const float rstd = rsqrtf(var + 1e-6f);
        short8v pk;
        #pragma unroll
        for (int j = 0; j < 8; ++j) {
            float v = (vals[j] - mean) * rstd * lnw[qu * 8 + j] + lnb[qu * 8 + j];
            if (SILU) v = v * sigm(v);
            pk[j] = f2bf(v);
        }
        *reinterpret_cast<short8v*>(&sXT2[p * 128 + ((qu * 8) ^ ((p & 7) << 3))]) = pk;
    }
    __syncthreads();

    // ---- conv2 MFMA + bias -> global ----
    {
        float4v a0 = {0.f, 0.f, 0.f, 0.f}, a1 = {0.f, 0.f, 0.f, 0.f};
        #pragma unroll
        for (int kk = 0; kk < 4; ++kk) {
            const int ki = kk * 32 + g * 8;
            const short8v af = *reinterpret_cast<const short8v*>(&sW2[arow + (ki ^ asw)]);
            const short8v bf0 = *reinterpret_cast<const short8v*>(&sXT2[p0 * 128 + (ki ^ bsw0)]);
            const short8v bf1 = *reinterpret_cast<const short8v*>(&sXT2[p1 * 128 + (ki ^ bsw1)]);
            a0 = __builtin_amdgcn_mfma_f32_16x16x32_bf16(af, bf0, a0, 0, 0, 0);
            a1 = __builtin_amdgcn_mfma_f32_16x16x32_bf16(af, bf1, a1, 0, 0, 0);
        }
        const float4 bv = *reinterpret_cast<const float4*>(&b2[tm * 16 + g * 4]);
        float* obase = out + (b * CDIM * HH + h) * WW;
        #pragma unroll
        for (int r = 0; r < 4; ++r) {
            const float bias = ((const float*)&bv)[r];
            obase[(tm * 16 + g * 4 + r) * HH * WW + p0] = a0[r] + bias;
            obase[(tm * 16 + g * 4 + r) * HH * WW + p1] = a1[r] + bias;
        }
    }
}

// ---- sim = <patch, center>/sqrt(C); softmax over 49; * gaussian spatial kernel
__global__ __launch_bounds__(1024) void simsoftmax_kernel(
    const float* __restrict__ px, const float* __restrict__ sigma_p,
    float* __restrict__ combined)
{
    __shared__ alignas(16) float sP[32][DD * WW];
    __shared__ float sSim[DSQ][WW];

    const int tid = threadIdx.x;
    const int w = tid & 63;
    const int q = tid >> 6;            // 0..15
    const int b = blockIdx.x >> 6;
    const int h = blockIdx.x & 63;

    int offk[4];
    #pragma unroll
    for (int k = 0; k < 4; ++k) {
        int n = q + 16 * k; if (n > 48) n = 48;
        const int ki = n / 7, kj = n % 7;
        offk[k] = ki * WW + reflect64(w + kj - RR);
    }

    float sim[4];
    #pragma unroll
    for (int k = 0; k < 4; ++k) sim[k] = 0.f;

    const float* pb = px + b * CDIM * HH * WW;
    for (int cc = 0; cc < 4; ++cc) {
        __syncthreads();
        for (int idx = tid; idx < 32 * DD * 16; idx += 1024) {
            const int pos = idx & 15;
            const int rk  = idx >> 4;
            const int cl  = rk / 7;
            const int ki  = rk - cl * 7;
            const int hp  = reflect64(h + ki - RR);
            *reinterpret_cast<float4*>(&sP[cl][ki * WW + pos * 4]) =
                *reinterpret_cast<const float4*>(
                    &pb[(cc * 32 + cl) * HH * WW + hp * WW + pos * 4]);
        }
        __syncthreads();
        #pragma unroll
        for (int cl = 0; cl < 32; ++cl) {
            const float xc = sP[cl][RR * WW + w];
            #pragma unroll
            for (int k = 0; k < 4; ++k)
                sim[k] = fmaf(sP[cl][offk[k]], xc, sim[k]);
        }
    }

    const float rscale = 0.088388347648318447f;  // 1/sqrt(128)
    #pragma unroll
    for (int k = 0; k < 4; ++k) {
        const int n = q + 16 * k;
        if (n < DSQ) sSim[n][w] = sim[k] * rscale;
    }
    __syncthreads();
    float m = -1e30f;
    #pragma unroll
    for (int n = 0; n < DSQ; ++n) m = fmaxf(m, sSim[n][w]);
    float ssum = 0.f;
    #pragma unroll
    for (int n = 0; n < DSQ; ++n) ssum += __expf(sSim[n][w] - m);
    const float inv = 1.0f / ssum;
    const float sigma = sigma_p[0];
    const float inv2s2 = 1.0f / (2.0f * sigma * sigma);
    float* cb = combined + (b * DSQ * HH + h) * WW;
    #pragma unroll
    for (int k = 0; k < 4; ++k) {
        const int n = q + 16 * k;
        if (n < DSQ) {
            const int ki = n / 7, kj = n % 7;
            const float dx = (float)(ki - 3) * (1.0f / 3.0f);
            const float dy = (float)(kj - 3) * (1.0f / 3.0f);
            const float sk = __expf(-(dx * dx + dy * dy) * inv2s2);
            cb[n * HH * WW + w] = __expf(sim[k] * rscale - m) * inv * sk;
        }
    }
}

// ---- fixup: conv(177->49) -> LN(49) -> SiLU -> conv(49->49) -> gate -> normalize
__global__ __launch_bounds__(1024) void fixup_kernel(
    const float* __restrict__ combined, const float* __restrict__ sem,
    const float* __restrict__ w1, const float* __restrict__ b1,
    const float* __restrict__ lnw, const float* __restrict__ lnb,
    const float* __restrict__ w2, const float* __restrict__ b2,
    float* __restrict__ wts)
{
    __shared__ alignas(16) float sCmb[52][WW];      // rows 49..51 zero
    __shared__ alignas(16) float sSem[CDIM][WW];
    __shared__ alignas(16) float sG[52][WW];        // rows 49..51 zero
    __shared__ alignas(16) float sW1a[DSQ][52];     // w1[:, 0:49], cols 49..51 zero
    __shared__ alignas(16) float sW1b[DSQ][CDIM];   // w1[:, 49:177]
    __shared__ alignas(16) float sW2[DSQ][52];      // w2, cols 49..51 zero
    __shared__ float red1[16][WW];
    __shared__ float red2[16][WW];

    const int tid = threadIdx.x;
    const int w = tid & 63;
    const int q = tid >> 6;            // 0..15
    const int qu = __builtin_amdgcn_readfirstlane(q);
    const int b = blockIdx.x >> 6;
    const int h = blockIdx.x & 63;

    const float* crow = combined + (b * DSQ * HH + h) * WW;
    for (int idx = tid; idx < 52 * 16; idx += 1024) {
        const int r = idx >> 4, pos = idx & 15;
        float4 v = make_float4(0.f, 0.f, 0.f, 0.f);
        if (r < DSQ) v = *reinterpret_cast<const float4*>(&crow[r * HH * WW + pos * 4]);
        *reinterpret_cast<float4*>(&sCmb[r][pos * 4]) = v;
    }
    const float* srow = sem + (b * CDIM * HH + h) * WW;
    for (int idx = tid; idx < CDIM * 16; idx += 1024) {
        const int r = idx >> 4, pos = idx & 15;
        *reinterpret_cast<float4*>(&sSem[r][pos * 4]) =
            *reinterpret_cast<const float4*>(&srow[r * HH * WW + pos * 4]);
    }
    for (int idx = tid; idx < DSQ * 52; idx += 1024) {
        const int r = idx / 52, c = idx - r * 52;
        sW1a[r][c] = (c < DSQ) ? w1[r * 177 + c] : 0.f;
        sW2[r][c]  = (c < DSQ) ? w2[r * DSQ + c] : 0.f;
    }
    for (int idx = tid; idx < DSQ * CDIM; idx += 1024) {
        const int r = idx >> 7, c = idx & 127;
        sW1b[r][c] = w1[r * 177 + DSQ + c];
    }
    if (tid < 3 * 64) sG[DSQ + (tid >> 6)][tid & 63] = 0.f;
    __syncthreads();

    int ok[4];
    #pragma unroll
    for (int k = 0; k < 4; ++k) {
        int o = qu + 16 * k; if (o > 48) o = 48;
        ok[k] = o;
    }

    float g[4];
    #pragma unroll
    for (int k = 0; k < 4; ++k) g[k] = b1[ok[k]];
    #pragma unroll 2
    for (int i = 0; i < 52; i += 4) {
        const float x0 = sCmb[i][w], x1 = sCmb[i+1][w], x2 = sCmb[i+2][w], x3 = sCmb[i+3][w];
        #pragma unroll
        for (int k = 0; k < 4; ++k) {
            const float4 wv = *reinterpret_cast<const float4*>(&sW1a[ok[k]][i]);
            g[k] = fmaf(wv.x, x0, fmaf(wv.y, x1, fmaf(wv.z, x2, fmaf(wv.w, x3, g[k]))));
        }
    }
    #pragma unroll 2
    for (int c = 0; c < CDIM; c += 4) {
        const float x0 = sSem[c][w], x1 = sSem[c+1][w], x2 = sSem[c+2][w], x3 = sSem[c+3][w];
        #pragma unroll
        for (int k = 0; k < 4; ++k) {
            const float4 wv = *reinterpret_cast<const float4*>(&sW1b[ok[k]][c]);
            g[k] = fmaf(wv.x, x0, fmaf(wv.y, x1, fmaf(wv.z, x2, fmaf(wv.w, x3, g[k]))));
        }
    }
    float s1 = 0.f, s2 = 0.f;
    #pragma unroll
    for (int k = 0; k < 4; ++k)
        if (q + 16 * k < DSQ) { s1 += g[k]; s2 += g[k] * g[k]; }
    red1[q][w] = s1; red2[q][w] = s2;
    __syncthreads();
    float t1 = 0.f, t2 = 0.f;
    #pragma unroll
    for (int j = 0; j < 16; ++j) { t1 += red1[j][w]; t2 += red2[j][w]; }
    const float mean = t1 * (1.0f / 49.0f);
    const float var  = t2 * (1.0f / 49.0f) - mean * mean;
    const float rstd = rsqrtf(var + 1e-6f);
    #pragma unroll
    for (int k = 0; k < 4; ++k) {
        const int o = q + 16 * k;
        if (o < DSQ) {
            float v = (g[k] - mean) * rstd * lnw[ok[k]] + lnb[ok[k]];
            sG[o][w] = v * sigm(v);
        }
    }
    __syncthreads();
    float f[4];
    #pragma unroll
    for (int k = 0; k < 4; ++k) f[k] = b2[ok[k]];
    #pragma unroll 2
    for (int i = 0; i < 52; i += 4) {
        const float x0 = sG[i][w], x1 = sG[i+1][w], x2 = sG[i+2][w], x3 = sG[i+3][w];
        #pragma unroll
        for (int k = 0; k < 4; ++k) {
            const float4 wv = *reinterpret_cast<const float4*>(&sW2[ok[k]][i]);
            f[k] = fmaf(wv.x, x0, fmaf(wv.y, x1, fmaf(wv.z, x2, fmaf(wv.w, x3, f[k]))));
        }
    }
    float c2[4];
    float ps = 0.f;
    #pragma unroll
    for (int k = 0; k < 4; ++k) {
        const int o = q + 16 * k;
        if (o < DSQ) {
            c2[k] = sCmb[o][w] * (1.0f + sigm(f[k]));
            ps += c2[k];
        } else c2[k] = 0.f;
    }
    red1[q][w] = ps;
    __syncthreads();
    float tot = 0.f;
    #pragma unroll
    for (int j = 0; j < 16; ++j) tot += red1[j][w];
    const float invt = 1.0f / (tot + 1e-7f);
    float* wrow = wts + (b * DSQ * HH + h) * WW;
    #pragma unroll
    for (int k = 0; k < 4; ++k) {
        const int o = q + 16 * k;
        if (o < DSQ) wrow[o * HH * WW + w] = c2[k] * invt;
    }
}

// ---- out0[c] = sum_n spatial[c, nbr(n)] * wts[n]
__global__ __launch_bounds__(1024) void aggregate_kernel(
    const float* __restrict__ spatial, const float* __restrict__ wts,
    float* __restrict__ out)
{
    __shared__ alignas(16) float sS[32][DD * WW];

    const int tid = threadIdx.x;
    const int w = tid & 63;
    const int q = tid >> 6;
    const int b = blockIdx.x >> 6;
    const int h = blockIdx.x & 63;

    float wv[DSQ];
    {
        const float* wrow = wts + (b * DSQ * HH + h) * WW + w;
        #pragma unroll
        for (int n = 0; n < DSQ; ++n) wv[n] = wrow[n * HH * WW];
    }
    int coff[DD];
    #pragma unroll
    for (int kj = 0; kj < DD; ++kj) coff[kj] = reflect64(w + kj - RR);

    const float* sb = spatial + b * CDIM * HH * WW;
    float* orow = out + (b * CDIM * HH + h) * WW;
    const int c0 = q * 2;

    for (int cc = 0; cc < 4; ++cc) {
        __syncthreads();
        for (int idx = tid; idx < 32 * DD * 16; idx += 1024) {
            const int pos = idx & 15;
            const int rk  = idx >> 4;
            const int cl  = rk / 7;
            const int ki  = rk - cl * 7;
            const int hp  = reflect64(h + ki - RR);
            *reinterpret_cast<float4*>(&sS[cl][ki * WW + pos * 4]) =
                *reinterpret_cast<const float4*>(
                    &sb[(cc * 32 + cl) * HH * WW + hp * WW + pos * 4]);
        }
        __syncthreads();
        float acc0 = 0.f, acc1 = 0.f;
        #pragma unroll
        for (int n = 0; n < DSQ; ++n) {
            const int ki = n / 7, kj = n % 7;       // compile-time
            const int off = ki * WW + coff[kj];
            acc0 = fmaf(sS[c0][off],     wv[n], acc0);
            acc1 = fmaf(sS[c0 + 1][off], wv[n], acc1);
        }
        orow[(cc * 32 + c0) * HH * WW + w]     = acc0;
        orow[(cc * 32 + c0 + 1) * HH * WW + w] = acc1;
    }
}

extern "C" void kernel_launch(void* const* d_in, const int* in_sizes, int n_in,
                              void* d_out, int out_size, void* d_ws, size_t ws_size,
                              hipStream_t stream) {
    (void)in_sizes; (void)n_in; (void)out_size; (void)ws_size;
    const float* spatial  = (const float*)d_in[0];
    const float* semantic = (const float*)d_in[1];
    const float* rp_w1 = (const float*)d_in[2];
    const float* rp_b1 = (const float*)d_in[3];
    const float* rp_lnw = (const float*)d_in[4];
    const float* rp_lnb = (const float*)d_in[5];
    const float* rp_w2 = (const float*)d_in[6];
    const float* rp_b2 = (const float*)d_in[7];
    const float* fx_w1 = (const float*)d_in[8];
    const float* fx_b1 = (const float*)d_in[9];
    const float* fx_lnw = (const float*)d_in[10];
    const float* fx_lnb = (const float*)d_in[11];
    const float* fx_w2 = (const float*)d_in[12];
    const float* fx_b2 = (const float*)d_in[13];
    const float* sigma = (const float*)d_in[14];
    const float* op_w1 = (const float*)d_in[15];
    const float* op_b1 = (const float*)d_in[16];
    const float* op_lnw = (const float*)d_in[17];
    const float* op_lnb = (const float*)d_in[18];
    const float* op_w2 = (const float*)d_in[19];
    const float* op_b2 = (const float*)d_in[20];

    float* ws = (float*)d_ws;
    float* proj_x   = ws;                       // 2,097,152 floats
    float* combined = ws + 2097152;             //   802,816 floats
    float* wtsbuf   = ws + 2899968;             //   802,816 floats
    float* agg      = proj_x;                   // reuse (proj_x dead after simsoftmax)
    float* outp     = (float*)d_out;

    dim3 grid(BB * HH), blk(1024);
    proj_kernel<true><<<grid, blk, 0, stream>>>(semantic, rp_w1, rp_b1, rp_lnw, rp_lnb,
                                                rp_w2, rp_b2, proj_x);
    simsoftmax_kernel<<<grid, blk, 0, stream>>>(proj_x, sigma, combined);
    fixup_kernel<<<grid, blk, 0, stream>>>(combined, semantic, fx_w1, fx_b1, fx_lnw,
                                           fx_lnb, fx_w2, fx_b2, wtsbuf);
    aggregate_kernel<<<grid, blk, 0, stream>>>(spatial, wtsbuf, agg);
    proj_kernel<false><<<grid, blk, 0, stream>>>(agg, op_w1, op_b1, op_lnw, op_lnb,
                                                 op_w2, op_b2, outp);
}

// Round 10
// 80.365 us; speedup vs baseline: 2.9820x; 1.0450x over previous
//
#include <hip/hip_runtime.h>
#include <cstdint>

#define BB 4
#define CDIM 128
#define HH 64
#define WW 64
#define RR 3
#define DD 7
#define DSQ 49

typedef __attribute__((ext_vector_type(8))) short short8v;   // 8 bf16 = 4 VGPR
typedef __attribute__((ext_vector_type(4))) float float4v;

__device__ __forceinline__ int reflect64(int p) {
    p = (p < 0) ? -p : p;
    return (p > 63) ? (126 - p) : p;
}
__device__ __forceinline__ float sigm(float x) { return 1.0f / (1.0f + __expf(-x)); }
__device__ __forceinline__ short f2bf(float f) {     // f32 -> bf16 RNE
    uint32_t u = __float_as_uint(f);
    u += 0x7FFF + ((u >> 16) & 1);
    return (short)(u >> 16);
}

// ---- range_proj: conv1x1 -> LN -> SiLU -> conv1x1 via bf16 MFMA (one (b,h) row per block)
template<bool SILU>
__global__ __launch_bounds__(1024) void proj_kernel(
    const float* __restrict__ x, const float* __restrict__ w1,
    const float* __restrict__ b1, const float* __restrict__ lnw,
    const float* __restrict__ lnb, const float* __restrict__ w2,
    const float* __restrict__ b2, float* __restrict__ out)
{
    __shared__ short sW1[CDIM * CDIM];   // 32 KB
    __shared__ short sW2[CDIM * CDIM];   // 32 KB
    __shared__ short sXT[WW * CDIM];     // 16 KB
    __shared__ short sXT2[WW * CDIM];    // 16 KB
    __shared__ float sT[CDIM][65];       // 33 KB
    __shared__ float red1[16][WW];
    __shared__ float red2[16][WW];

    const int tid = threadIdx.x;
    const int l = tid & 63;
    const int q = tid >> 6;
    const int qu = __builtin_amdgcn_readfirstlane(q);
    const int b = blockIdx.x >> 6;
    const int h = blockIdx.x & 63;

    {
        const int o = tid >> 3;
        const int i0 = (tid & 7) * 16;
        const int sw = (o & 7) << 3;
        const float* wsrc[2] = {w1, w2};
        short* wdst[2] = {sW1, sW2};
        #pragma unroll
        for (int m = 0; m < 2; ++m) {
            const float* src = wsrc[m] + o * CDIM + i0;
            short8v pk0, pk1;
            #pragma unroll
            for (int j = 0; j < 8; ++j) pk0[j] = f2bf(src[j]);
            #pragma unroll
            for (int j = 0; j < 8; ++j) pk1[j] = f2bf(src[8 + j]);
            *reinterpret_cast<short8v*>(&wdst[m][o * 128 + (i0 ^ sw)]) = pk0;
            *reinterpret_cast<short8v*>(&wdst[m][o * 128 + ((i0 + 8) ^ sw)]) = pk1;
        }
    }
    {
        const int pos = tid & 15;
        const int c0 = tid >> 4;
        const float* xrow = x + (b * CDIM * HH + h) * WW;
        #pragma unroll
        for (int rr = 0; rr < 2; ++rr) {
            const int c = c0 + rr * 64;
            const float4 v = *reinterpret_cast<const float4*>(&xrow[c * HH * WW + pos * 4]);
            #pragma unroll
            for (int m = 0; m < 4; ++m) {
                const int p = pos * 4 + m;
                sXT[p * 128 + (c ^ ((p & 7) << 3))] = f2bf(((const float*)&v)[m]);
            }
        }
    }
    __syncthreads();

    const int lm = l & 15, g = l >> 4;
    const int tm = q >> 1;
    const int tn0 = (q & 1) * 2;
    const int oa = tm * 16 + lm;
    const int arow = oa * 128, asw = (oa & 7) << 3;
    const int p0 = tn0 * 16 + lm, p1 = (tn0 + 1) * 16 + lm;
    const int bsw0 = (p0 & 7) << 3, bsw1 = (p1 & 7) << 3;

    float4v acc0 = {0.f, 0.f, 0.f, 0.f}, acc1 = {0.f, 0.f, 0.f, 0.f};
    #pragma unroll
    for (int kk = 0; kk < 4; ++kk) {
        const int ki = kk * 32 + g * 8;
        const short8v af = *reinterpret_cast<const short8v*>(&sW1[arow + (ki ^ asw)]);
        const short8v bf0 = *reinterpret_cast<const short8v*>(&sXT[p0 * 128 + (ki ^ bsw0)]);
        const short8v bf1 = *reinterpret_cast<const short8v*>(&sXT[p1 * 128 + (ki ^ bsw1)]);
        acc0 = __builtin_amdgcn_mfma_f32_16x16x32_bf16(af, bf0, acc0, 0, 0, 0);
        acc1 = __builtin_amdgcn_mfma_f32_16x16x32_bf16(af, bf1, acc1, 0, 0, 0);
    }
    #pragma unroll
    for (int r = 0; r < 4; ++r) sT[tm * 16 + g * 4 + r][p0] = acc0[r];
    #pragma unroll
    for (int r = 0; r < 4; ++r) sT[tm * 16 + g * 4 + r][p1] = acc1[r];
    __syncthreads();

    {
        const int p = l;
        float vals[8];
        float s1 = 0.f, s2 = 0.f;
        #pragma unroll
        for (int j = 0; j < 8; ++j) {
            const float v = sT[qu * 8 + j][p] + b1[qu * 8 + j];
            vals[j] = v; s1 += v; s2 += v * v;
        }
        red1[q][p] = s1; red2[q][p] = s2;
        __syncthreads();
        float t1 = 0.f, t2 = 0.f;
        #pragma unroll
        for (int j = 0; j < 16; ++j) { t1 += red1[j][p]; t2 += red2[j][p]; }
        const float mean = t1 * (1.0f / 128.0f);
        const float var  = t2 * (1.0f / 128.0f) - mean * mean;
        const float rstd = rsqrtf(var + 1e-6f);
        short8v pk;
        #pragma unroll
        for (int j = 0; j < 8; ++j) {
            float v = (vals[j] - mean) * rstd * lnw[qu * 8 + j] + lnb[qu * 8 + j];
            if (SILU) v = v * sigm(v);
            pk[j] = f2bf(v);
        }
        *reinterpret_cast<short8v*>(&sXT2[p * 128 + ((qu * 8) ^ ((p & 7) << 3))]) = pk;
    }
    __syncthreads();

    {
        float4v a0 = {0.f, 0.f, 0.f, 0.f}, a1 = {0.f, 0.f, 0.f, 0.f};
        #pragma unroll
        for (int kk = 0; kk < 4; ++kk) {
            const int ki = kk * 32 + g * 8;
            const short8v af = *reinterpret_cast<const short8v*>(&sW2[arow + (ki ^ asw)]);
            const short8v bf0 = *reinterpret_cast<const short8v*>(&sXT2[p0 * 128 + (ki ^ bsw0)]);
            const short8v bf1 = *reinterpret_cast<const short8v*>(&sXT2[p1 * 128 + (ki ^ bsw1)]);
            a0 = __builtin_amdgcn_mfma_f32_16x16x32_bf16(af, bf0, a0, 0, 0, 0);
            a1 = __builtin_amdgcn_mfma_f32_16x16x32_bf16(af, bf1, a1, 0, 0, 0);
        }
        const float4 bv = *reinterpret_cast<const float4*>(&b2[tm * 16 + g * 4]);
        float* obase = out + (b * CDIM * HH + h) * WW;
        #pragma unroll
        for (int r = 0; r < 4; ++r) {
            const float bias = ((const float*)&bv)[r];
            obase[(tm * 16 + g * 4 + r) * HH * WW + p0] = a0[r] + bias;
            obase[(tm * 16 + g * 4 + r) * HH * WW + p1] = a1[r] + bias;
        }
    }
}

// ---- fused: sim+softmax*spatial (combined stays in LDS) -> fixup -> wts (global)
__global__ __launch_bounds__(1024) void simfix_kernel(
    const float* __restrict__ px, const float* __restrict__ sigma_p,
    const float* __restrict__ sem,
    const float* __restrict__ w1, const float* __restrict__ b1,
    const float* __restrict__ lnw, const float* __restrict__ lnb,
    const float* __restrict__ w2, const float* __restrict__ b2,
    float* __restrict__ wts)
{
    __shared__ alignas(16) char sBufA[32 * DD * WW * 4];   // 57.3 KB: sP | {sSem, sG}
    __shared__ alignas(16) float sW1a[DSQ][52];
    __shared__ alignas(16) float sW1b[DSQ][CDIM];
    __shared__ alignas(16) float sW2f[DSQ][52];
    __shared__ alignas(16) float sCmb[52][WW];
    __shared__ alignas(16) float sSim[DSQ][WW];
    __shared__ float red1[16][WW];
    __shared__ float red2[16][WW];

    float (*sP)[DD * WW] = reinterpret_cast<float(*)[DD * WW]>(sBufA);
    float (*sSem)[WW]    = reinterpret_cast<float(*)[WW]>(sBufA);
    float (*sG)[WW]      = reinterpret_cast<float(*)[WW]>(sBufA + CDIM * WW * 4);

    const int tid = threadIdx.x;
    const int w = tid & 63;
    const int q = tid >> 6;
    const int qu = __builtin_amdgcn_readfirstlane(q);
    const int b = blockIdx.x >> 6;
    const int h = blockIdx.x & 63;

    // fixup weights (dedicated regions) + sCmb pad rows
    for (int idx = tid; idx < DSQ * 52; idx += 1024) {
        const int r = idx / 52, c = idx - r * 52;
        sW1a[r][c] = (c < DSQ) ? w1[r * 177 + c] : 0.f;
        sW2f[r][c] = (c < DSQ) ? w2[r * DSQ + c] : 0.f;
    }
    for (int idx = tid; idx < DSQ * CDIM; idx += 1024) {
        const int r = idx >> 7, c = idx & 127;
        sW1b[r][c] = w1[r * 177 + DSQ + c];
    }
    if (tid < 3 * 64) sCmb[DSQ + (tid >> 6)][tid & 63] = 0.f;

    // ---- sim phase ----
    int offk[4];
    #pragma unroll
    for (int k = 0; k < 4; ++k) {
        int n = q + 16 * k; if (n > 48) n = 48;
        const int ki = n / 7, kj = n % 7;
        offk[k] = ki * WW + reflect64(w + kj - RR);
    }
    float sim[4] = {0.f, 0.f, 0.f, 0.f};
    const float* pb = px + b * CDIM * HH * WW;
    for (int cc = 0; cc < 4; ++cc) {
        __syncthreads();
        for (int idx = tid; idx < 32 * DD * 16; idx += 1024) {
            const int pos = idx & 15;
            const int rk  = idx >> 4;
            const int cl  = rk / 7;
            const int ki  = rk - cl * 7;
            const int hp  = reflect64(h + ki - RR);
            *reinterpret_cast<float4*>(&sP[cl][ki * WW + pos * 4]) =
                *reinterpret_cast<const float4*>(
                    &pb[(cc * 32 + cl) * HH * WW + hp * WW + pos * 4]);
        }
        __syncthreads();
        #pragma unroll
        for (int cl = 0; cl < 32; ++cl) {
            const float xc = sP[cl][RR * WW + w];
            #pragma unroll
            for (int k = 0; k < 4; ++k)
                sim[k] = fmaf(sP[cl][offk[k]], xc, sim[k]);
        }
    }

    const float rscale = 0.088388347648318447f;  // 1/sqrt(128)
    #pragma unroll
    for (int k = 0; k < 4; ++k) {
        const int n = q + 16 * k;
        if (n < DSQ) sSim[n][w] = sim[k] * rscale;
    }
    __syncthreads();                 // after this, sP is dead (all reads done)
    float m = -1e30f;
    #pragma unroll
    for (int n = 0; n < DSQ; ++n) m = fmaxf(m, sSim[n][w]);
    float ssum = 0.f;
    #pragma unroll
    for (int n = 0; n < DSQ; ++n) ssum += __expf(sSim[n][w] - m);
    const float inv = 1.0f / ssum;
    const float sigma = sigma_p[0];
    const float inv2s2 = 1.0f / (2.0f * sigma * sigma);
    #pragma unroll
    for (int k = 0; k < 4; ++k) {
        const int n = q + 16 * k;
        if (n < DSQ) {
            const int ki = n / 7, kj = n % 7;
            const float dx = (float)(ki - 3) * (1.0f / 3.0f);
            const float dy = (float)(kj - 3) * (1.0f / 3.0f);
            const float sk = __expf(-(dx * dx + dy * dy) * inv2s2);
            sCmb[n][w] = __expf(sim[k] * rscale - m) * inv * sk;
        }
    }
    // stage sSem over dead sP; zero sG pad rows
    const float* srow = sem + (b * CDIM * HH + h) * WW;
    for (int idx = tid; idx < CDIM * 16; idx += 1024) {
        const int r = idx >> 4, pos = idx & 15;
        *reinterpret_cast<float4*>(&sSem[r][pos * 4]) =
            *reinterpret_cast<const float4*>(&srow[r * HH * WW + pos * 4]);
    }
    if (tid < 3 * 64) sG[DSQ + (tid >> 6)][tid & 63] = 0.f;
    __syncthreads();

    // ---- fixup ----
    int ok[4];
    #pragma unroll
    for (int k = 0; k < 4; ++k) {
        int o = qu + 16 * k; if (o > 48) o = 48;
        ok[k] = o;
    }
    float g[4];
    #pragma unroll
    for (int k = 0; k < 4; ++k) g[k] = b1[ok[k]];
    #pragma unroll 2
    for (int i = 0; i < 52; i += 4) {
        const float x0 = sCmb[i][w], x1 = sCmb[i+1][w], x2 = sCmb[i+2][w], x3 = sCmb[i+3][w];
        #pragma unroll
        for (int k = 0; k < 4; ++k) {
            const float4 wv = *reinterpret_cast<const float4*>(&sW1a[ok[k]][i]);
            g[k] = fmaf(wv.x, x0, fmaf(wv.y, x1, fmaf(wv.z, x2, fmaf(wv.w, x3, g[k]))));
        }
    }
    #pragma unroll 2
    for (int c = 0; c < CDIM; c += 4) {
        const float x0 = sSem[c][w], x1 = sSem[c+1][w], x2 = sSem[c+2][w], x3 = sSem[c+3][w];
        #pragma unroll
        for (int k = 0; k < 4; ++k) {
            const float4 wv = *reinterpret_cast<const float4*>(&sW1b[ok[k]][c]);
            g[k] = fmaf(wv.x, x0, fmaf(wv.y, x1, fmaf(wv.z, x2, fmaf(wv.w, x3, g[k]))));
        }
    }
    float s1 = 0.f, s2 = 0.f;
    #pragma unroll
    for (int k = 0; k < 4; ++k)
        if (q + 16 * k < DSQ) { s1 += g[k]; s2 += g[k] * g[k]; }
    red1[q][w] = s1; red2[q][w] = s2;
    __syncthreads();
    float t1 = 0.f, t2 = 0.f;
    #pragma unroll
    for (int j = 0; j < 16; ++j) { t1 += red1[j][w]; t2 += red2[j][w]; }
    const float mean = t1 * (1.0f / 49.0f);
    const float var  = t2 * (1.0f / 49.0f) - mean * mean;
    const float rstd = rsqrtf(var + 1e-6f);
    #pragma unroll
    for (int k = 0; k < 4; ++k) {
        const int o = q + 16 * k;
        if (o < DSQ) {
            float v = (g[k] - mean) * rstd * lnw[ok[k]] + lnb[ok[k]];
            sG[o][w] = v * sigm(v);
        }
    }
    __syncthreads();
    float f[4];
    #pragma unroll
    for (int k = 0; k < 4; ++k) f[k] = b2[ok[k]];
    #pragma unroll 2
    for (int i = 0; i < 52; i += 4) {
        const float x0 = sG[i][w], x1 = sG[i+1][w], x2 = sG[i+2][w], x3 = sG[i+3][w];
        #pragma unroll
        for (int k = 0; k < 4; ++k) {
            const float4 wv = *reinterpret_cast<const float4*>(&sW2f[ok[k]][i]);
            f[k] = fmaf(wv.x, x0, fmaf(wv.y, x1, fmaf(wv.z, x2, fmaf(wv.w, x3, f[k]))));
        }
    }
    float c2[4];
    float ps = 0.f;
    #pragma unroll
    for (int k = 0; k < 4; ++k) {
        const int o = q + 16 * k;
        if (o < DSQ) {
            c2[k] = sCmb[o][w] * (1.0f + sigm(f[k]));
            ps += c2[k];
        } else c2[k] = 0.f;
    }
    red1[q][w] = ps;
    __syncthreads();
    float tot = 0.f;
    #pragma unroll
    for (int j = 0; j < 16; ++j) tot += red1[j][w];
    const float invt = 1.0f / (tot + 1e-7f);
    float* wrow = wts + (b * DSQ * HH + h) * WW;
    #pragma unroll
    for (int k = 0; k < 4; ++k) {
        const int o = q + 16 * k;
        if (o < DSQ) wrow[o * HH * WW + w] = c2[k] * invt;
    }
}

// ---- fused: aggregate -> (bf16 sXT) -> output_proj conv-LN-conv MFMA -> d_out
__global__ __launch_bounds__(1024) void aggproj_kernel(
    const float* __restrict__ spatial, const float* __restrict__ wts,
    const float* __restrict__ w1, const float* __restrict__ b1,
    const float* __restrict__ lnw, const float* __restrict__ lnb,
    const float* __restrict__ w2, const float* __restrict__ b2,
    float* __restrict__ out)
{
    __shared__ alignas(16) char sBufC[32 * DD * WW * 4];   // 57.3 KB: sS | sT
    __shared__ short sWb[CDIM * CDIM];   // 32 KB bf16: w1 then w2
    __shared__ short sXT[WW * CDIM];     // 16 KB
    __shared__ short sXT2[WW * CDIM];    // 16 KB
    __shared__ float red1[16][WW];
    __shared__ float red2[16][WW];

    float (*sS)[DD * WW] = reinterpret_cast<float(*)[DD * WW]>(sBufC);
    float (*sT)[65]      = reinterpret_cast<float(*)[65]>(sBufC);

    const int tid = threadIdx.x;
    const int l = tid & 63;
    const int q = tid >> 6;
    const int qu = __builtin_amdgcn_readfirstlane(q);
    const int b = blockIdx.x >> 6;
    const int h = blockIdx.x & 63;

    // stage op_w1 bf16 swizzled
    {
        const int o = tid >> 3;
        const int i0 = (tid & 7) * 16;
        const int sw = (o & 7) << 3;
        const float* src = w1 + o * CDIM + i0;
        short8v pk0, pk1;
        #pragma unroll
        for (int j = 0; j < 8; ++j) pk0[j] = f2bf(src[j]);
        #pragma unroll
        for (int j = 0; j < 8; ++j) pk1[j] = f2bf(src[8 + j]);
        *reinterpret_cast<short8v*>(&sWb[o * 128 + (i0 ^ sw)]) = pk0;
        *reinterpret_cast<short8v*>(&sWb[o * 128 + ((i0 + 8) ^ sw)]) = pk1;
    }
    // preload 49 weights + reflected col offsets
    float wv[DSQ];
    {
        const float* wrow = wts + (b * DSQ * HH + h) * WW + l;
        #pragma unroll
        for (int n = 0; n < DSQ; ++n) wv[n] = wrow[n * HH * WW];
    }
    int coff[DD];
    #pragma unroll
    for (int kj = 0; kj < DD; ++kj) coff[kj] = reflect64(l + kj - RR);

    const float* sb = spatial + b * CDIM * HH * WW;
    // ---- aggregate, writing bf16 transposed operand directly ----
    for (int cc = 0; cc < 4; ++cc) {
        __syncthreads();
        for (int idx = tid; idx < 32 * DD * 16; idx += 1024) {
            const int pos = idx & 15;
            const int rk  = idx >> 4;
            const int cl  = rk / 7;
            const int ki  = rk - cl * 7;
            const int hp  = reflect64(h + ki - RR);
            *reinterpret_cast<float4*>(&sS[cl][ki * WW + pos * 4]) =
                *reinterpret_cast<const float4*>(
                    &sb[(cc * 32 + cl) * HH * WW + hp * WW + pos * 4]);
        }
        __syncthreads();
        float acc0 = 0.f, acc1 = 0.f;
        const int c0 = q * 2;
        #pragma unroll
        for (int n = 0; n < DSQ; ++n) {
            const int ki = n / 7, kj = n % 7;       // compile-time
            const int off = ki * WW + coff[kj];
            acc0 = fmaf(sS[c0][off],     wv[n], acc0);
            acc1 = fmaf(sS[c0 + 1][off], wv[n], acc1);
        }
        const int cg = cc * 32 + c0;
        const int p = l, psw = (p & 7) << 3;
        sXT[p * 128 + (cg ^ psw)]       = f2bf(acc0);
        sXT[p * 128 + ((cg + 1) ^ psw)] = f2bf(acc1);
    }
    __syncthreads();          // sXT complete; sS dead

    const int lm = l & 15, g = l >> 4;
    const int tm = q >> 1;
    const int tn0 = (q & 1) * 2;
    const int oa = tm * 16 + lm;
    const int arow = oa * 128, asw = (oa & 7) << 3;
    const int p0 = tn0 * 16 + lm, p1 = (tn0 + 1) * 16 + lm;
    const int bsw0 = (p0 & 7) << 3, bsw1 = (p1 & 7) << 3;

    // ---- conv1 MFMA ----
    float4v acc0 = {0.f, 0.f, 0.f, 0.f}, acc1 = {0.f, 0.f, 0.f, 0.f};
    #pragma unroll
    for (int kk = 0; kk < 4; ++kk) {
        const int ki = kk * 32 + g * 8;
        const short8v af = *reinterpret_cast<const short8v*>(&sWb[arow + (ki ^ asw)]);
        const short8v bf0 = *reinterpret_cast<const short8v*>(&sXT[p0 * 128 + (ki ^ bsw0)]);
        const short8v bf1 = *reinterpret_cast<const short8v*>(&sXT[p1 * 128 + (ki ^ bsw1)]);
        acc0 = __builtin_amdgcn_mfma_f32_16x16x32_bf16(af, bf0, acc0, 0, 0, 0);
        acc1 = __builtin_amdgcn_mfma_f32_16x16x32_bf16(af, bf1, acc1, 0, 0, 0);
    }
    #pragma unroll
    for (int r = 0; r < 4; ++r) sT[tm * 16 + g * 4 + r][p0] = acc0[r];
    #pragma unroll
    for (int r = 0; r < 4; ++r) sT[tm * 16 + g * 4 + r][p1] = acc1[r];
    __syncthreads();          // conv1 done: sWb reads finished, sT complete

    // ---- restage sWb = w2, plus bias + LN (no SiLU) -> sXT2 ----
    {
        const int o = tid >> 3;
        const int i0 = (tid & 7) * 16;
        const int sw = (o & 7) << 3;
        const float* src = w2 + o * CDIM + i0;
        short8v pk0, pk1;
        #pragma unroll
        for (int j = 0; j < 8; ++j) pk0[j] = f2bf(src[j]);
        #pragma unroll
        for (int j = 0; j < 8; ++j) pk1[j] = f2bf(src[8 + j]);
        *reinterpret_cast<short8v*>(&sWb[o * 128 + (i0 ^ sw)]) = pk0;
        *reinterpret_cast<short8v*>(&sWb[o * 128 + ((i0 + 8) ^ sw)]) = pk1;
    }
    {
        const int p = l;
        float vals[8];
        float s1 = 0.f, s2 = 0.f;
        #pragma unroll
        for (int j = 0; j < 8; ++j) {
            const float v = sT[qu * 8 + j][p] + b1[qu * 8 + j];
            vals[j] = v; s1 += v; s2 += v * v;
        }
        red1[q][p] = s1; red2[q][p] = s2;
        __syncthreads();
        float t1 = 0.f, t2 = 0.f;
        #pragma unroll
        for (int j = 0; j < 16; ++j) { t1 += red1[j][p]; t2 += red2[j][p]; }
        const float mean = t1 * (1.0f / 128.0f);
        const float var  = t2 * (1.0f / 128.0f) - mean * mean;
        const float rstd = rsqrtf(var + 1e-6f);
        short8v pk;
        #pragma unroll
        for (int j = 0; j < 8; ++j) {
            const float v = (vals[j] - mean) * rstd * lnw[qu * 8 + j] + lnb[qu * 8 + j];
            pk[j] = f2bf(v);
        }
        *reinterpret_cast<short8v*>(&sXT2[p * 128 + ((qu * 8) ^ ((p & 7) << 3))]) = pk;
    }
    __syncthreads();

    // ---- conv2 MFMA + bias -> out ----
    {
        float4v a0 = {0.f, 0.f, 0.f, 0.f}, a1 = {0.f, 0.f, 0.f, 0.f};
        #pragma unroll
        for (int kk = 0; kk < 4; ++kk) {
            const int ki = kk * 32 + g * 8;
            const short8v af = *reinterpret_cast<const short8v*>(&sWb[arow + (ki ^ asw)]);
            const short8v bf0 = *reinterpret_cast<const short8v*>(&sXT2[p0 * 128 + (ki ^ bsw0)]);
            const short8v bf1 = *reinterpret_cast<const short8v*>(&sXT2[p1 * 128 + (ki ^ bsw1)]);
            a0 = __builtin_amdgcn_mfma_f32_16x16x32_bf16(af, bf0, a0, 0, 0, 0);
            a1 = __builtin_amdgcn_mfma_f32_16x16x32_bf16(af, bf1, a1, 0, 0, 0);
        }
        const float4 bv = *reinterpret_cast<const float4*>(&b2[tm * 16 + g * 4]);
        float* obase = out + (b * CDIM * HH + h) * WW;
        #pragma unroll
        for (int r = 0; r < 4; ++r) {
            const float bias = ((const float*)&bv)[r];
            obase[(tm * 16 + g * 4 + r) * HH * WW + p0] = a0[r] + bias;
            obase[(tm * 16 + g * 4 + r) * HH * WW + p1] = a1[r] + bias;
        }
    }
}

extern "C" void kernel_launch(void* const* d_in, const int* in_sizes, int n_in,
                              void* d_out, int out_size, void* d_ws, size_t ws_size,
                              hipStream_t stream) {
    (void)in_sizes; (void)n_in; (void)out_size; (void)ws_size;
    const float* spatial  = (const float*)d_in[0];
    const float* semantic = (const float*)d_in[1];
    const float* rp_w1 = (const float*)d_in[2];
    const float* rp_b1 = (const float*)d_in[3];
    const float* rp_lnw = (const float*)d_in[4];
    const float* rp_lnb = (const float*)d_in[5];
    const float* rp_w2 = (const float*)d_in[6];
    const float* rp_b2 = (const float*)d_in[7];
    const float* fx_w1 = (const float*)d_in[8];
    const float* fx_b1 = (const float*)d_in[9];
    const float* fx_lnw = (const float*)d_in[10];
    const float* fx_lnb = (const float*)d_in[11];
    const float* fx_w2 = (const float*)d_in[12];
    const float* fx_b2 = (const float*)d_in[13];
    const float* sigma = (const float*)d_in[14];
    const float* op_w1 = (const float*)d_in[15];
    const float* op_b1 = (const float*)d_in[16];
    const float* op_lnw = (const float*)d_in[17];
    const float* op_lnb = (const float*)d_in[18];
    const float* op_w2 = (const float*)d_in[19];
    const float* op_b2 = (const float*)d_in[20];

    float* ws = (float*)d_ws;
    float* proj_x = ws;                         // 2,097,152 floats
    float* wtsbuf = ws + 2097152;               //   802,816 floats
    float* outp   = (float*)d_out;

    dim3 grid(BB * HH), blk(1024);
    proj_kernel<true><<<grid, blk, 0, stream>>>(semantic, rp_w1, rp_b1, rp_lnw, rp_lnb,
                                                rp_w2, rp_b2, proj_x);
    simfix_kernel<<<grid, blk, 0, stream>>>(proj_x, sigma, semantic, fx_w1, fx_b1,
                                            fx_lnw, fx_lnb, fx_w2, fx_b2, wtsbuf);
    aggproj_kernel<<<grid, blk, 0, stream>>>(spatial, wtsbuf, op_w1, op_b1, op_lnw,
                                             op_lnb, op_w2, op_b2, outp);
}

// Round 11
// 74.864 us; speedup vs baseline: 3.2011x; 1.0735x over previous
//
#include <hip/hip_runtime.h>
#include <cstdint>

#define BB 4
#define CDIM 128
#define HH 64
#define WW 64
#define RR 3
#define DD 7
#define DSQ 49

typedef __attribute__((ext_vector_type(8))) short short8v;   // 8 bf16 = 4 VGPR
typedef __attribute__((ext_vector_type(4))) float float4v;

__device__ __forceinline__ int reflect64(int p) {
    p = (p < 0) ? -p : p;
    return (p > 63) ? (126 - p) : p;
}
__device__ __forceinline__ float sigm(float x) { return 1.0f / (1.0f + __expf(-x)); }
__device__ __forceinline__ short f2bf(float f) {     // f32 -> bf16 RNE
    uint32_t u = __float_as_uint(f);
    u += 0x7FFF + ((u >> 16) & 1);
    return (short)(u >> 16);
}

// ---- range_proj: conv1x1 -> LN -> SiLU -> conv1x1 via bf16 MFMA.
// Output: bf16 TRANSPOSED [b][h][p][c] (feeds simfix's Gram MFMA directly).
template<bool SILU>
__global__ __launch_bounds__(1024) void proj_kernel(
    const float* __restrict__ x, const float* __restrict__ w1,
    const float* __restrict__ b1, const float* __restrict__ lnw,
    const float* __restrict__ lnb, const float* __restrict__ w2,
    const float* __restrict__ b2, short* __restrict__ outT)
{
    __shared__ short sW1[CDIM * CDIM];   // 32 KB
    __shared__ short sW2[CDIM * CDIM];   // 32 KB
    __shared__ short sXT[WW * CDIM];     // 16 KB
    __shared__ short sXT2[WW * CDIM];    // 16 KB
    __shared__ float sT[CDIM][65];       // 33 KB
    __shared__ float red1[16][WW];
    __shared__ float red2[16][WW];

    const int tid = threadIdx.x;
    const int l = tid & 63;
    const int q = tid >> 6;
    const int qu = __builtin_amdgcn_readfirstlane(q);
    const int b = blockIdx.x >> 6;
    const int h = blockIdx.x & 63;

    {
        const int o = tid >> 3;
        const int i0 = (tid & 7) * 16;
        const int sw = (o & 7) << 3;
        const float* wsrc[2] = {w1, w2};
        short* wdst[2] = {sW1, sW2};
        #pragma unroll
        for (int m = 0; m < 2; ++m) {
            const float* src = wsrc[m] + o * CDIM + i0;
            short8v pk0, pk1;
            #pragma unroll
            for (int j = 0; j < 8; ++j) pk0[j] = f2bf(src[j]);
            #pragma unroll
            for (int j = 0; j < 8; ++j) pk1[j] = f2bf(src[8 + j]);
            *reinterpret_cast<short8v*>(&wdst[m][o * 128 + (i0 ^ sw)]) = pk0;
            *reinterpret_cast<short8v*>(&wdst[m][o * 128 + ((i0 + 8) ^ sw)]) = pk1;
        }
    }
    {
        const int pos = tid & 15;
        const int c0 = tid >> 4;
        const float* xrow = x + (b * CDIM * HH + h) * WW;
        #pragma unroll
        for (int rr = 0; rr < 2; ++rr) {
            const int c = c0 + rr * 64;
            const float4 v = *reinterpret_cast<const float4*>(&xrow[c * HH * WW + pos * 4]);
            #pragma unroll
            for (int m = 0; m < 4; ++m) {
                const int p = pos * 4 + m;
                sXT[p * 128 + (c ^ ((p & 7) << 3))] = f2bf(((const float*)&v)[m]);
            }
        }
    }
    __syncthreads();

    const int lm = l & 15, g = l >> 4;
    const int tm = q >> 1;
    const int tn0 = (q & 1) * 2;
    const int oa = tm * 16 + lm;
    const int arow = oa * 128, asw = (oa & 7) << 3;
    const int p0 = tn0 * 16 + lm, p1 = (tn0 + 1) * 16 + lm;
    const int bsw0 = (p0 & 7) << 3, bsw1 = (p1 & 7) << 3;

    float4v acc0 = {0.f, 0.f, 0.f, 0.f}, acc1 = {0.f, 0.f, 0.f, 0.f};
    #pragma unroll
    for (int kk = 0; kk < 4; ++kk) {
        const int ki = kk * 32 + g * 8;
        const short8v af = *reinterpret_cast<const short8v*>(&sW1[arow + (ki ^ asw)]);
        const short8v bf0 = *reinterpret_cast<const short8v*>(&sXT[p0 * 128 + (ki ^ bsw0)]);
        const short8v bf1 = *reinterpret_cast<const short8v*>(&sXT[p1 * 128 + (ki ^ bsw1)]);
        acc0 = __builtin_amdgcn_mfma_f32_16x16x32_bf16(af, bf0, acc0, 0, 0, 0);
        acc1 = __builtin_amdgcn_mfma_f32_16x16x32_bf16(af, bf1, acc1, 0, 0, 0);
    }
    #pragma unroll
    for (int r = 0; r < 4; ++r) sT[tm * 16 + g * 4 + r][p0] = acc0[r];
    #pragma unroll
    for (int r = 0; r < 4; ++r) sT[tm * 16 + g * 4 + r][p1] = acc1[r];
    __syncthreads();

    {
        const int p = l;
        float vals[8];
        float s1 = 0.f, s2 = 0.f;
        #pragma unroll
        for (int j = 0; j < 8; ++j) {
            const float v = sT[qu * 8 + j][p] + b1[qu * 8 + j];
            vals[j] = v; s1 += v; s2 += v * v;
        }
        red1[q][p] = s1; red2[q][p] = s2;
        __syncthreads();
        float t1 = 0.f, t2 = 0.f;
        #pragma unroll
        for (int j = 0; j < 16; ++j) { t1 += red1[j][p]; t2 += red2[j][p]; }
        const float mean = t1 * (1.0f / 128.0f);
        const float var  = t2 * (1.0f / 128.0f) - mean * mean;
        const float rstd = rsqrtf(var + 1e-6f);
        short8v pk;
        #pragma unroll
        for (int j = 0; j < 8; ++j) {
            float v = (vals[j] - mean) * rstd * lnw[qu * 8 + j] + lnb[qu * 8 + j];
            if (SILU) v = v * sigm(v);
            pk[j] = f2bf(v);
        }
        *reinterpret_cast<short8v*>(&sXT2[p * 128 + ((qu * 8) ^ ((p & 7) << 3))]) = pk;
    }
    __syncthreads();

    {
        float4v a0 = {0.f, 0.f, 0.f, 0.f}, a1 = {0.f, 0.f, 0.f, 0.f};
        #pragma unroll
        for (int kk = 0; kk < 4; ++kk) {
            const int ki = kk * 32 + g * 8;
            const short8v af = *reinterpret_cast<const short8v*>(&sW2[arow + (ki ^ asw)]);
            const short8v bf0 = *reinterpret_cast<const short8v*>(&sXT2[p0 * 128 + (ki ^ bsw0)]);
            const short8v bf1 = *reinterpret_cast<const short8v*>(&sXT2[p1 * 128 + (ki ^ bsw1)]);
            a0 = __builtin_amdgcn_mfma_f32_16x16x32_bf16(af, bf0, a0, 0, 0, 0);
            a1 = __builtin_amdgcn_mfma_f32_16x16x32_bf16(af, bf1, a1, 0, 0, 0);
        }
        const float4 bv = *reinterpret_cast<const float4*>(&b2[tm * 16 + g * 4]);
        #pragma unroll
        for (int r = 0; r < 4; ++r) {
            const float bias = ((const float*)&bv)[r];
            sT[tm * 16 + g * 4 + r][p0] = a0[r] + bias;
            sT[tm * 16 + g * 4 + r][p1] = a1[r] + bias;
        }
    }
    __syncthreads();
    // transposed bf16 write: [b][h][p][c]
    {
        const int p = tid >> 4;
        const int c0 = (tid & 15) * 8;
        short8v pk;
        #pragma unroll
        for (int j = 0; j < 8; ++j) pk[j] = f2bf(sT[c0 + j][p]);
        *reinterpret_cast<short8v*>(&outT[((b * HH + h) * WW + p) * CDIM + c0]) = pk;
    }
}

// ---- fused: Gram-MFMA sim -> softmax*spatial -> fixup -> wts
__global__ __launch_bounds__(1024) void simfix_kernel(
    const short* __restrict__ pxt, const float* __restrict__ sigma_p,
    const float* __restrict__ sem,
    const float* __restrict__ w1, const float* __restrict__ b1,
    const float* __restrict__ lnw, const float* __restrict__ lnb,
    const float* __restrict__ w2, const float* __restrict__ b2,
    float* __restrict__ wts)
{
    __shared__ alignas(16) char sBig[7 * WW * CDIM * 2];   // 114,688 B
    __shared__ alignas(16) float sP64[64][66];             // 16,896 B
    __shared__ alignas(16) float sSim[DSQ][WW];            // 12,544 B
    __shared__ alignas(16) float sCmb[52][WW];             // 13,312 B
    __shared__ float red1[16][WW];                         //  4,096 B

    short* rows = reinterpret_cast<short*>(sBig);          // 7 x [64][128] bf16 swizzled
    float* fW1a = reinterpret_cast<float*>(sBig);          // [49][52]
    float* fW1b = fW1a + DSQ * 52;                         // [49][128]
    float* fW2  = fW1b + DSQ * CDIM;                       // [49][52]
    float* fSem = fW2 + DSQ * 52;                          // [128][64]
    float* fG   = fSem + CDIM * WW;                        // [52][64]

    const int tid = threadIdx.x;
    const int l = tid & 63;
    const int q = tid >> 6;
    const int qu = __builtin_amdgcn_readfirstlane(q);
    const int b = blockIdx.x >> 6;
    const int h = blockIdx.x & 63;

    // ---- stage 7 reflected rows, bf16 [row][p][c] with c ^= (p&7)<<3 ----
    for (int idx = tid; idx < 7 * WW * 16; idx += 1024) {
        const int cchunk = idx & 15;
        const int p = (idx >> 4) & 63;
        const int row = idx >> 10;
        const int hp = reflect64(h + row - RR);
        const short8v v = *reinterpret_cast<const short8v*>(
            &pxt[((b * HH + hp) * WW + p) * CDIM + cchunk * 8]);
        *reinterpret_cast<short8v*>(
            &rows[(row * WW + p) * CDIM + ((cchunk * 8) ^ ((p & 7) << 3))]) = v;
    }
    if (tid < 192) sCmb[DSQ + (tid >> 6)][tid & 63] = 0.f;
    __syncthreads();

    // ---- Gram MFMA per ki: P_ki[p][p'] = sum_c Xc[c][p] * Xki[c][p'] ----
    const int lm = l & 15, g = l >> 4;
    const int tm = q >> 2, tn = q & 3;
    const int pa = tm * 16 + lm;
    const int pb = tn * 16 + lm;
    const int abase = (3 * WW + pa) * CDIM, as_ = (pa & 7) << 3;
    const int bs_ = (pb & 7) << 3;

    short8v afr[4];
    #pragma unroll
    for (int kk = 0; kk < 4; ++kk)
        afr[kk] = *reinterpret_cast<const short8v*>(
            &rows[abase + ((kk * 32 + g * 8) ^ as_)]);

    const float rscale = 0.088388347648318447f;  // 1/sqrt(128)
    for (int ki = 0; ki < 7; ++ki) {
        float4v acc = {0.f, 0.f, 0.f, 0.f};
        const int bbase = (ki * WW + pb) * CDIM;
        #pragma unroll
        for (int kk = 0; kk < 4; ++kk) {
            const short8v bf = *reinterpret_cast<const short8v*>(
                &rows[bbase + ((kk * 32 + g * 8) ^ bs_)]);
            acc = __builtin_amdgcn_mfma_f32_16x16x32_bf16(afr[kk], bf, acc, 0, 0, 0);
        }
        #pragma unroll
        for (int r = 0; r < 4; ++r)
            sP64[tm * 16 + g * 4 + r][tn * 16 + lm] = acc[r];
        __syncthreads();
        if (tid < 448) {
            const int kj = tid >> 6, p = tid & 63;
            sSim[ki * 7 + kj][p] = sP64[p][reflect64(p + kj - RR)] * rscale;
        }
        __syncthreads();
    }

    // ---- stage fixup weights + sem into overlay (rows dead); softmax in parallel ----
    for (int idx = tid; idx < DSQ * 52; idx += 1024) {
        const int r = idx / 52, c = idx - r * 52;
        fW1a[idx] = (c < DSQ) ? w1[r * 177 + c] : 0.f;
        fW2[idx]  = (c < DSQ) ? w2[r * DSQ + c] : 0.f;
    }
    for (int idx = tid; idx < DSQ * CDIM; idx += 1024) {
        const int r = idx >> 7, c = idx & 127;
        fW1b[idx] = w1[r * 177 + DSQ + c];
    }
    {
        const float* srow = sem + (b * CDIM * HH + h) * WW;
        for (int idx = tid; idx < CDIM * 16; idx += 1024) {
            const int r = idx >> 4, pos = idx & 15;
            *reinterpret_cast<float4*>(&fSem[r * WW + pos * 4]) =
                *reinterpret_cast<const float4*>(&srow[r * HH * WW + pos * 4]);
        }
    }
    if (tid < 192) fG[(DSQ + (tid >> 6)) * WW + (tid & 63)] = 0.f;

    // softmax (each thread handles pixel l; 16-way redundant across waves)
    {
        float rv[DSQ];
        #pragma unroll
        for (int n = 0; n < DSQ; ++n) rv[n] = sSim[n][l];
        float m = -1e30f;
        #pragma unroll
        for (int n = 0; n < DSQ; ++n) m = fmaxf(m, rv[n]);
        float ssum = 0.f;
        #pragma unroll
        for (int n = 0; n < DSQ; ++n) ssum += __expf(rv[n] - m);
        const float inv = 1.0f / ssum;
        const float sigma = sigma_p[0];
        const float inv2s2 = 1.0f / (2.0f * sigma * sigma);
        #pragma unroll
        for (int k = 0; k < 4; ++k) {
            const int n = q + 16 * k;
            if (n < DSQ) {
                const int ki = n / 7, kj = n % 7;
                const float dx = (float)(ki - 3) * (1.0f / 3.0f);
                const float dy = (float)(kj - 3) * (1.0f / 3.0f);
                const float sk = __expf(-(dx * dx + dy * dy) * inv2s2);
                sCmb[n][l] = __expf(rv[n] - m) * inv * sk;
            }
        }
    }
    __syncthreads();

    // ---- fixup: conv(177->49) -> LN -> SiLU -> conv(49->49) -> gate -> normalize ----
    int ok[4];
    #pragma unroll
    for (int k = 0; k < 4; ++k) {
        int o = qu + 16 * k; if (o > 48) o = 48;
        ok[k] = o;
    }
    float gacc[4];
    #pragma unroll
    for (int k = 0; k < 4; ++k) gacc[k] = b1[ok[k]];
    #pragma unroll 2
    for (int i = 0; i < 52; i += 4) {
        const float x0 = sCmb[i][l], x1 = sCmb[i+1][l], x2 = sCmb[i+2][l], x3 = sCmb[i+3][l];
        #pragma unroll
        for (int k = 0; k < 4; ++k) {
            const float4 wv = *reinterpret_cast<const float4*>(&fW1a[ok[k] * 52 + i]);
            gacc[k] = fmaf(wv.x, x0, fmaf(wv.y, x1, fmaf(wv.z, x2, fmaf(wv.w, x3, gacc[k]))));
        }
    }
    #pragma unroll 2
    for (int c = 0; c < CDIM; c += 4) {
        const float x0 = fSem[c * WW + l], x1 = fSem[(c+1) * WW + l],
                    x2 = fSem[(c+2) * WW + l], x3 = fSem[(c+3) * WW + l];
        #pragma unroll
        for (int k = 0; k < 4; ++k) {
            const float4 wv = *reinterpret_cast<const float4*>(&fW1b[ok[k] * CDIM + c]);
            gacc[k] = fmaf(wv.x, x0, fmaf(wv.y, x1, fmaf(wv.z, x2, fmaf(wv.w, x3, gacc[k]))));
        }
    }
    float s1 = 0.f, s2 = 0.f;
    #pragma unroll
    for (int k = 0; k < 4; ++k)
        if (q + 16 * k < DSQ) { s1 += gacc[k]; s2 += gacc[k] * gacc[k]; }
    red1[q][l] = s1;
    __syncthreads();
    float t1 = 0.f;
    #pragma unroll
    for (int j = 0; j < 16; ++j) t1 += red1[j][l];
    __syncthreads();
    red1[q][l] = s2;
    __syncthreads();
    float t2 = 0.f;
    #pragma unroll
    for (int j = 0; j < 16; ++j) t2 += red1[j][l];
    const float mean = t1 * (1.0f / 49.0f);
    const float var  = t2 * (1.0f / 49.0f) - mean * mean;
    const float rstd = rsqrtf(var + 1e-6f);
    #pragma unroll
    for (int k = 0; k < 4; ++k) {
        const int o = q + 16 * k;
        if (o < DSQ) {
            float v = (gacc[k] - mean) * rstd * lnw[ok[k]] + lnb[ok[k]];
            fG[o * WW + l] = v * sigm(v);
        }
    }
    __syncthreads();
    float fa[4];
    #pragma unroll
    for (int k = 0; k < 4; ++k) fa[k] = b2[ok[k]];
    #pragma unroll 2
    for (int i = 0; i < 52; i += 4) {
        const float x0 = fG[i * WW + l], x1 = fG[(i+1) * WW + l],
                    x2 = fG[(i+2) * WW + l], x3 = fG[(i+3) * WW + l];
        #pragma unroll
        for (int k = 0; k < 4; ++k) {
            const float4 wv = *reinterpret_cast<const float4*>(&fW2[ok[k] * 52 + i]);
            fa[k] = fmaf(wv.x, x0, fmaf(wv.y, x1, fmaf(wv.z, x2, fmaf(wv.w, x3, fa[k]))));
        }
    }
    float c2[4];
    float ps = 0.f;
    #pragma unroll
    for (int k = 0; k < 4; ++k) {
        const int o = q + 16 * k;
        if (o < DSQ) {
            c2[k] = sCmb[o][l] * (1.0f + sigm(fa[k]));
            ps += c2[k];
        } else c2[k] = 0.f;
    }
    red1[q][l] = ps;
    __syncthreads();
    float tot = 0.f;
    #pragma unroll
    for (int j = 0; j < 16; ++j) tot += red1[j][l];
    const float invt = 1.0f / (tot + 1e-7f);
    float* wrow = wts + (b * DSQ * HH + h) * WW;
    #pragma unroll
    for (int k = 0; k < 4; ++k) {
        const int o = q + 16 * k;
        if (o < DSQ) wrow[o * HH * WW + l] = c2[k] * invt;
    }
}

// ---- fused: aggregate -> (bf16 sXT) -> output_proj conv-LN-conv MFMA -> d_out
__global__ __launch_bounds__(1024) void aggproj_kernel(
    const float* __restrict__ spatial, const float* __restrict__ wts,
    const float* __restrict__ w1, const float* __restrict__ b1,
    const float* __restrict__ lnw, const float* __restrict__ lnb,
    const float* __restrict__ w2, const float* __restrict__ b2,
    float* __restrict__ out)
{
    __shared__ alignas(16) char sBufC[32 * DD * WW * 4];   // 57.3 KB: sS | sT
    __shared__ short sWb[CDIM * CDIM];   // 32 KB bf16: w1 then w2
    __shared__ short sXT[WW * CDIM];     // 16 KB
    __shared__ short sXT2[WW * CDIM];    // 16 KB
    __shared__ float red1[16][WW];
    __shared__ float red2[16][WW];

    float (*sS)[DD * WW] = reinterpret_cast<float(*)[DD * WW]>(sBufC);
    float (*sT)[65]      = reinterpret_cast<float(*)[65]>(sBufC);

    const int tid = threadIdx.x;
    const int l = tid & 63;
    const int q = tid >> 6;
    const int qu = __builtin_amdgcn_readfirstlane(q);
    const int b = blockIdx.x >> 6;
    const int h = blockIdx.x & 63;

    {
        const int o = tid >> 3;
        const int i0 = (tid & 7) * 16;
        const int sw = (o & 7) << 3;
        const float* src = w1 + o * CDIM + i0;
        short8v pk0, pk1;
        #pragma unroll
        for (int j = 0; j < 8; ++j) pk0[j] = f2bf(src[j]);
        #pragma unroll
        for (int j = 0; j < 8; ++j) pk1[j] = f2bf(src[8 + j]);
        *reinterpret_cast<short8v*>(&sWb[o * 128 + (i0 ^ sw)]) = pk0;
        *reinterpret_cast<short8v*>(&sWb[o * 128 + ((i0 + 8) ^ sw)]) = pk1;
    }
    float wv[DSQ];
    {
        const float* wrow = wts + (b * DSQ * HH + h) * WW + l;
        #pragma unroll
        for (int n = 0; n < DSQ; ++n) wv[n] = wrow[n * HH * WW];
    }
    int coff[DD];
    #pragma unroll
    for (int kj = 0; kj < DD; ++kj) coff[kj] = reflect64(l + kj - RR);

    const float* sb = spatial + b * CDIM * HH * WW;
    for (int cc = 0; cc < 4; ++cc) {
        __syncthreads();
        for (int idx = tid; idx < 32 * DD * 16; idx += 1024) {
            const int pos = idx & 15;
            const int rk  = idx >> 4;
            const int cl  = rk / 7;
            const int ki  = rk - cl * 7;
            const int hp  = reflect64(h + ki - RR);
            *reinterpret_cast<float4*>(&sS[cl][ki * WW + pos * 4]) =
                *reinterpret_cast<const float4*>(
                    &sb[(cc * 32 + cl) * HH * WW + hp * WW + pos * 4]);
        }
        __syncthreads();
        float acc0 = 0.f, acc1 = 0.f;
        const int c0 = q * 2;
        #pragma unroll
        for (int n = 0; n < DSQ; ++n) {
            const int ki = n / 7, kj = n % 7;       // compile-time
            const int off = ki * WW + coff[kj];
            acc0 = fmaf(sS[c0][off],     wv[n], acc0);
            acc1 = fmaf(sS[c0 + 1][off], wv[n], acc1);
        }
        const int cg = cc * 32 + c0;
        const int p = l, psw = (p & 7) << 3;
        sXT[p * 128 + (cg ^ psw)]       = f2bf(acc0);
        sXT[p * 128 + ((cg + 1) ^ psw)] = f2bf(acc1);
    }
    __syncthreads();

    const int lm = l & 15, g = l >> 4;
    const int tm = q >> 1;
    const int tn0 = (q & 1) * 2;
    const int oa = tm * 16 + lm;
    const int arow = oa * 128, asw = (oa & 7) << 3;
    const int p0 = tn0 * 16 + lm, p1 = (tn0 + 1) * 16 + lm;
    const int bsw0 = (p0 & 7) << 3, bsw1 = (p1 & 7) << 3;

    float4v acc0 = {0.f, 0.f, 0.f, 0.f}, acc1 = {0.f, 0.f, 0.f, 0.f};
    #pragma unroll
    for (int kk = 0; kk < 4; ++kk) {
        const int ki = kk * 32 + g * 8;
        const short8v af = *reinterpret_cast<const short8v*>(&sWb[arow + (ki ^ asw)]);
        const short8v bf0 = *reinterpret_cast<const short8v*>(&sXT[p0 * 128 + (ki ^ bsw0)]);
        const short8v bf1 = *reinterpret_cast<const short8v*>(&sXT[p1 * 128 + (ki ^ bsw1)]);
        acc0 = __builtin_amdgcn_mfma_f32_16x16x32_bf16(af, bf0, acc0, 0, 0, 0);
        acc1 = __builtin_amdgcn_mfma_f32_16x16x32_bf16(af, bf1, acc1, 0, 0, 0);
    }
    #pragma unroll
    for (int r = 0; r < 4; ++r) sT[tm * 16 + g * 4 + r][p0] = acc0[r];
    #pragma unroll
    for (int r = 0; r < 4; ++r) sT[tm * 16 + g * 4 + r][p1] = acc1[r];
    __syncthreads();

    {
        const int o = tid >> 3;
        const int i0 = (tid & 7) * 16;
        const int sw = (o & 7) << 3;
        const float* src = w2 + o * CDIM + i0;
        short8v pk0, pk1;
        #pragma unroll
        for (int j = 0; j < 8; ++j) pk0[j] = f2bf(src[j]);
        #pragma unroll
        for (int j = 0; j < 8; ++j) pk1[j] = f2bf(src[8 + j]);
        *reinterpret_cast<short8v*>(&sWb[o * 128 + (i0 ^ sw)]) = pk0;
        *reinterpret_cast<short8v*>(&sWb[o * 128 + ((i0 + 8) ^ sw)]) = pk1;
    }
    {
        const int p = l;
        float vals[8];
        float s1 = 0.f, s2 = 0.f;
        #pragma unroll
        for (int j = 0; j < 8; ++j) {
            const float v = sT[qu * 8 + j][p] + b1[qu * 8 + j];
            vals[j] = v; s1 += v; s2 += v * v;
        }
        red1[q][p] = s1; red2[q][p] = s2;
        __syncthreads();
        float t1 = 0.f, t2 = 0.f;
        #pragma unroll
        for (int j = 0; j < 16; ++j) { t1 += red1[j][p]; t2 += red2[j][p]; }
        const float mean = t1 * (1.0f / 128.0f);
        const float var  = t2 * (1.0f / 128.0f) - mean * mean;
        const float rstd = rsqrtf(var + 1e-6f);
        short8v pk;
        #pragma unroll
        for (int j = 0; j < 8; ++j) {
            const float v = (vals[j] - mean) * rstd * lnw[qu * 8 + j] + lnb[qu * 8 + j];
            pk[j] = f2bf(v);
        }
        *reinterpret_cast<short8v*>(&sXT2[p * 128 + ((qu * 8) ^ ((p & 7) << 3))]) = pk;
    }
    __syncthreads();

    {
        float4v a0 = {0.f, 0.f, 0.f, 0.f}, a1 = {0.f, 0.f, 0.f, 0.f};
        #pragma unroll
        for (int kk = 0; kk < 4; ++kk) {
            const int ki = kk * 32 + g * 8;
            const short8v af = *reinterpret_cast<const short8v*>(&sWb[arow + (ki ^ asw)]);
            const short8v bf0 = *reinterpret_cast<const short8v*>(&sXT2[p0 * 128 + (ki ^ bsw0)]);
            const short8v bf1 = *reinterpret_cast<const short8v*>(&sXT2[p1 * 128 + (ki ^ bsw1)]);
            a0 = __builtin_amdgcn_mfma_f32_16x16x32_bf16(af, bf0, a0, 0, 0, 0);
            a1 = __builtin_amdgcn_mfma_f32_16x16x32_bf16(af, bf1, a1, 0, 0, 0);
        }
        const float4 bv = *reinterpret_cast<const float4*>(&b2[tm * 16 + g * 4]);
        float* obase = out + (b * CDIM * HH + h) * WW;
        #pragma unroll
        for (int r = 0; r < 4; ++r) {
            const float bias = ((const float*)&bv)[r];
            obase[(tm * 16 + g * 4 + r) * HH * WW + p0] = a0[r] + bias;
            obase[(tm * 16 + g * 4 + r) * HH * WW + p1] = a1[r] + bias;
        }
    }
}

extern "C" void kernel_launch(void* const* d_in, const int* in_sizes, int n_in,
                              void* d_out, int out_size, void* d_ws, size_t ws_size,
                              hipStream_t stream) {
    (void)in_sizes; (void)n_in; (void)out_size; (void)ws_size;
    const float* spatial  = (const float*)d_in[0];
    const float* semantic = (const float*)d_in[1];
    const float* rp_w1 = (const float*)d_in[2];
    const float* rp_b1 = (const float*)d_in[3];
    const float* rp_lnw = (const float*)d_in[4];
    const float* rp_lnb = (const float*)d_in[5];
    const float* rp_w2 = (const float*)d_in[6];
    const float* rp_b2 = (const float*)d_in[7];
    const float* fx_w1 = (const float*)d_in[8];
    const float* fx_b1 = (const float*)d_in[9];
    const float* fx_lnw = (const float*)d_in[10];
    const float* fx_lnb = (const float*)d_in[11];
    const float* fx_w2 = (const float*)d_in[12];
    const float* fx_b2 = (const float*)d_in[13];
    const float* sigma = (const float*)d_in[14];
    const float* op_w1 = (const float*)d_in[15];
    const float* op_b1 = (const float*)d_in[16];
    const float* op_lnw = (const float*)d_in[17];
    const float* op_lnb = (const float*)d_in[18];
    const float* op_w2 = (const float*)d_in[19];
    const float* op_b2 = (const float*)d_in[20];

    char* wsb = (char*)d_ws;
    short* pxt    = (short*)wsb;                             // 4 MB bf16 [b][h][p][c]
    float* wtsbuf = (float*)(wsb + 4u * 1024u * 1024u);      // 3.2 MB
    float* outp   = (float*)d_out;

    dim3 grid(BB * HH), blk(1024);
    proj_kernel<true><<<grid, blk, 0, stream>>>(semantic, rp_w1, rp_b1, rp_lnw, rp_lnb,
                                                rp_w2, rp_b2, pxt);
    simfix_kernel<<<grid, blk, 0, stream>>>(pxt, sigma, semantic, fx_w1, fx_b1,
                                            fx_lnw, fx_lnb, fx_w2, fx_b2, wtsbuf);
    aggproj_kernel<<<grid, blk, 0, stream>>>(spatial, wtsbuf, op_w1, op_b1, op_lnw,
                                             op_lnb, op_w2, op_b2, outp);
}

// Round 12
// 66.869 us; speedup vs baseline: 3.5838x; 1.1196x over previous
//
#include <hip/hip_runtime.h>
#include <cstdint>

#define BB 4
#define CDIM 128
#define HH 64
#define WW 64
#define RR 3
#define DD 7
#define DSQ 49

typedef __attribute__((ext_vector_type(8))) short short8v;   // 8 bf16 = 4 VGPR
typedef __attribute__((ext_vector_type(4))) float float4v;

__device__ __forceinline__ int reflect64(int p) {
    p = (p < 0) ? -p : p;
    return (p > 63) ? (126 - p) : p;
}
__device__ __forceinline__ float sigm(float x) { return 1.0f / (1.0f + __expf(-x)); }
__device__ __forceinline__ short f2bf(float f) {     // f32 -> bf16 RNE
    uint32_t u = __float_as_uint(f);
    u += 0x7FFF + ((u >> 16) & 1);
    return (short)(u >> 16);
}

// ---- range_proj: conv1x1 -> LN -> SiLU -> conv1x1 via bf16 MFMA.
// Output: bf16 TRANSPOSED [b][h][p][c].
template<bool SILU>
__global__ __launch_bounds__(1024) void proj_kernel(
    const float* __restrict__ x, const float* __restrict__ w1,
    const float* __restrict__ b1, const float* __restrict__ lnw,
    const float* __restrict__ lnb, const float* __restrict__ w2,
    const float* __restrict__ b2, short* __restrict__ outT)
{
    __shared__ short sW1[CDIM * CDIM];
    __shared__ short sW2[CDIM * CDIM];
    __shared__ short sXT[WW * CDIM];
    __shared__ short sXT2[WW * CDIM];
    __shared__ float sT[CDIM][65];
    __shared__ float red1[16][WW];
    __shared__ float red2[16][WW];

    const int tid = threadIdx.x;
    const int l = tid & 63;
    const int q = tid >> 6;
    const int qu = __builtin_amdgcn_readfirstlane(q);
    const int b = blockIdx.x >> 6;
    const int h = blockIdx.x & 63;

    {
        const int o = tid >> 3;
        const int i0 = (tid & 7) * 16;
        const int sw = (o & 7) << 3;
        const float* wsrc[2] = {w1, w2};
        short* wdst[2] = {sW1, sW2};
        #pragma unroll
        for (int m = 0; m < 2; ++m) {
            const float* src = wsrc[m] + o * CDIM + i0;
            short8v pk0, pk1;
            #pragma unroll
            for (int j = 0; j < 8; ++j) pk0[j] = f2bf(src[j]);
            #pragma unroll
            for (int j = 0; j < 8; ++j) pk1[j] = f2bf(src[8 + j]);
            *reinterpret_cast<short8v*>(&wdst[m][o * 128 + (i0 ^ sw)]) = pk0;
            *reinterpret_cast<short8v*>(&wdst[m][o * 128 + ((i0 + 8) ^ sw)]) = pk1;
        }
    }
    {
        const int pos = tid & 15;
        const int c0 = tid >> 4;
        const float* xrow = x + (b * CDIM * HH + h) * WW;
        #pragma unroll
        for (int rr = 0; rr < 2; ++rr) {
            const int c = c0 + rr * 64;
            const float4 v = *reinterpret_cast<const float4*>(&xrow[c * HH * WW + pos * 4]);
            #pragma unroll
            for (int m = 0; m < 4; ++m) {
                const int p = pos * 4 + m;
                sXT[p * 128 + (c ^ ((p & 7) << 3))] = f2bf(((const float*)&v)[m]);
            }
        }
    }
    __syncthreads();

    const int lm = l & 15, g = l >> 4;
    const int tm = q >> 1;
    const int tn0 = (q & 1) * 2;
    const int oa = tm * 16 + lm;
    const int arow = oa * 128, asw = (oa & 7) << 3;
    const int p0 = tn0 * 16 + lm, p1 = (tn0 + 1) * 16 + lm;
    const int bsw0 = (p0 & 7) << 3, bsw1 = (p1 & 7) << 3;

    float4v acc0 = {0.f, 0.f, 0.f, 0.f}, acc1 = {0.f, 0.f, 0.f, 0.f};
    #pragma unroll
    for (int kk = 0; kk < 4; ++kk) {
        const int ki = kk * 32 + g * 8;
        const short8v af = *reinterpret_cast<const short8v*>(&sW1[arow + (ki ^ asw)]);
        const short8v bf0 = *reinterpret_cast<const short8v*>(&sXT[p0 * 128 + (ki ^ bsw0)]);
        const short8v bf1 = *reinterpret_cast<const short8v*>(&sXT[p1 * 128 + (ki ^ bsw1)]);
        acc0 = __builtin_amdgcn_mfma_f32_16x16x32_bf16(af, bf0, acc0, 0, 0, 0);
        acc1 = __builtin_amdgcn_mfma_f32_16x16x32_bf16(af, bf1, acc1, 0, 0, 0);
    }
    #pragma unroll
    for (int r = 0; r < 4; ++r) sT[tm * 16 + g * 4 + r][p0] = acc0[r];
    #pragma unroll
    for (int r = 0; r < 4; ++r) sT[tm * 16 + g * 4 + r][p1] = acc1[r];
    __syncthreads();

    {
        const int p = l;
        float vals[8];
        float s1 = 0.f, s2 = 0.f;
        #pragma unroll
        for (int j = 0; j < 8; ++j) {
            const float v = sT[qu * 8 + j][p] + b1[qu * 8 + j];
            vals[j] = v; s1 += v; s2 += v * v;
        }
        red1[q][p] = s1; red2[q][p] = s2;
        __syncthreads();
        float t1 = 0.f, t2 = 0.f;
        #pragma unroll
        for (int j = 0; j < 16; ++j) { t1 += red1[j][p]; t2 += red2[j][p]; }
        const float mean = t1 * (1.0f / 128.0f);
        const float var  = t2 * (1.0f / 128.0f) - mean * mean;
        const float rstd = rsqrtf(var + 1e-6f);
        short8v pk;
        #pragma unroll
        for (int j = 0; j < 8; ++j) {
            float v = (vals[j] - mean) * rstd * lnw[qu * 8 + j] + lnb[qu * 8 + j];
            if (SILU) v = v * sigm(v);
            pk[j] = f2bf(v);
        }
        *reinterpret_cast<short8v*>(&sXT2[p * 128 + ((qu * 8) ^ ((p & 7) << 3))]) = pk;
    }
    __syncthreads();

    {
        float4v a0 = {0.f, 0.f, 0.f, 0.f}, a1 = {0.f, 0.f, 0.f, 0.f};
        #pragma unroll
        for (int kk = 0; kk < 4; ++kk) {
            const int ki = kk * 32 + g * 8;
            const short8v af = *reinterpret_cast<const short8v*>(&sW2[arow + (ki ^ asw)]);
            const short8v bf0 = *reinterpret_cast<const short8v*>(&sXT2[p0 * 128 + (ki ^ bsw0)]);
            const short8v bf1 = *reinterpret_cast<const short8v*>(&sXT2[p1 * 128 + (ki ^ bsw1)]);
            a0 = __builtin_amdgcn_mfma_f32_16x16x32_bf16(af, bf0, a0, 0, 0, 0);
            a1 = __builtin_amdgcn_mfma_f32_16x16x32_bf16(af, bf1, a1, 0, 0, 0);
        }
        const float4 bv = *reinterpret_cast<const float4*>(&b2[tm * 16 + g * 4]);
        #pragma unroll
        for (int r = 0; r < 4; ++r) {
            const float bias = ((const float*)&bv)[r];
            sT[tm * 16 + g * 4 + r][p0] = a0[r] + bias;
            sT[tm * 16 + g * 4 + r][p1] = a1[r] + bias;
        }
    }
    __syncthreads();
    {
        const int p = tid >> 4;
        const int c0 = (tid & 15) * 8;
        short8v pk;
        #pragma unroll
        for (int j = 0; j < 8; ++j) pk[j] = f2bf(sT[c0 + j][p]);
        *reinterpret_cast<short8v*>(&outT[((b * HH + h) * WW + p) * CDIM + c0]) = pk;
    }
}

// ---- fused: Gram-MFMA sim -> softmax*spatial -> MFMA fixup -> wts
__global__ __launch_bounds__(1024) void simfix_kernel(
    const short* __restrict__ pxt, const float* __restrict__ sigma_p,
    const float* __restrict__ sem,
    const float* __restrict__ w1, const float* __restrict__ b1,
    const float* __restrict__ lnw, const float* __restrict__ lnb,
    const float* __restrict__ w2, const float* __restrict__ b2,
    float* __restrict__ wts)
{
    __shared__ alignas(16) char sBig[7 * WW * CDIM * 2];   // 114,688 B
    __shared__ alignas(16) char sAux[64 * 66 * 4];         //  16,896 B: sP64 | {red1,red2}
    __shared__ alignas(16) float sSim[DSQ][64];            //  12,544 B
    __shared__ alignas(16) float sCmb[DSQ][66];            //  12,936 B

    short* rows = reinterpret_cast<short*>(sBig);          // Gram: 7 x [64][128] bf16 swz
    // fixup overlay of sBig (rows dead after Gram):
    short* B1   = reinterpret_cast<short*>(sBig);          // [64 px][192] bf16 swz
    short* A1   = reinterpret_cast<short*>(sBig + 24576);  // [64 o ][192] bf16 swz
    short* B2   = reinterpret_cast<short*>(sBig + 49152);  // [64 px][64]  bf16 swz
    short* A2   = reinterpret_cast<short*>(sBig + 57344);  // [64 o ][64]  bf16 swz
    float* fSem = reinterpret_cast<float*>(sBig + 65536);  // [128][64] f32
    float* prm  = reinterpret_cast<float*>(sBig + 98304);  // b1p|lnwp|lnbp|b2p x64

    float (*sP64)[66] = reinterpret_cast<float(*)[66]>(sAux);
    float (*red1)[65] = reinterpret_cast<float(*)[65]>(sAux);
    float (*red2)[65] = reinterpret_cast<float(*)[65]>(sAux + 16 * 65 * 4);

    const int tid = threadIdx.x;
    const int l = tid & 63;
    const int q = tid >> 6;
    const int b = blockIdx.x >> 6;
    const int h = blockIdx.x & 63;

    // ---- stage 7 reflected rows, bf16 [row][p][c] swz ----
    for (int idx = tid; idx < 7 * WW * 16; idx += 1024) {
        const int cchunk = idx & 15;
        const int p = (idx >> 4) & 63;
        const int row = idx >> 10;
        const int hp = reflect64(h + row - RR);
        const short8v v = *reinterpret_cast<const short8v*>(
            &pxt[((b * HH + hp) * WW + p) * CDIM + cchunk * 8]);
        *reinterpret_cast<short8v*>(
            &rows[(row * WW + p) * CDIM + ((cchunk * 8) ^ ((p & 7) << 3))]) = v;
    }
    __syncthreads();

    // ---- Gram MFMA per ki ----
    const int lm = l & 15, g = l >> 4;
    const int tm = q >> 2, tn = q & 3;
    const int pa = tm * 16 + lm;
    const int pxb = tn * 16 + lm;
    const int abase = (3 * WW + pa) * CDIM, as_ = (pa & 7) << 3;
    const int bs_ = (pxb & 7) << 3;

    short8v afr[4];
    #pragma unroll
    for (int kk = 0; kk < 4; ++kk)
        afr[kk] = *reinterpret_cast<const short8v*>(
            &rows[abase + ((kk * 32 + g * 8) ^ as_)]);

    const float rscale = 0.088388347648318447f;  // 1/sqrt(128)
    for (int ki = 0; ki < 7; ++ki) {
        float4v acc = {0.f, 0.f, 0.f, 0.f};
        const int bbase = (ki * WW + pxb) * CDIM;
        #pragma unroll
        for (int kk = 0; kk < 4; ++kk) {
            const short8v bf = *reinterpret_cast<const short8v*>(
                &rows[bbase + ((kk * 32 + g * 8) ^ bs_)]);
            acc = __builtin_amdgcn_mfma_f32_16x16x32_bf16(afr[kk], bf, acc, 0, 0, 0);
        }
        #pragma unroll
        for (int r = 0; r < 4; ++r)
            sP64[tm * 16 + g * 4 + r][tn * 16 + lm] = acc[r];
        __syncthreads();
        if (tid < 448) {
            const int kj = tid >> 6, p = tid & 63;
            sSim[ki * 7 + kj][p] = sP64[p][reflect64(p + kj - RR)] * rscale;
        }
        __syncthreads();
    }
    // rows/sP64 now dead -> stage fixup operands into overlays.

    // A1: w1 -> bf16 [64][192], layout [0:49]=cmb-cols, [49:64]=0, [64:192]=sem-cols
    for (int idx = tid; idx < 64 * 24; idx += 1024) {
        const int o = idx / 24;
        const int ch0 = (idx % 24) * 8;
        short8v pk;
        #pragma unroll
        for (int j = 0; j < 8; ++j) {
            const int c = ch0 + j;
            float v = 0.f;
            if (o < DSQ) {
                if (c < DSQ) v = w1[o * 177 + c];
                else if (c >= 64) v = w1[o * 177 + DSQ + (c - 64)];
            }
            pk[j] = f2bf(v);
        }
        *reinterpret_cast<short8v*>(&A1[o * 192 + (ch0 ^ ((o & 7) << 3))]) = pk;
    }
    // A2: w2 -> bf16 [64][64], zero-padded
    for (int idx = tid; idx < 64 * 8; idx += 1024) {
        const int o = idx >> 3;
        const int ch0 = (idx & 7) * 8;
        short8v pk;
        #pragma unroll
        for (int j = 0; j < 8; ++j) {
            const int c = ch0 + j;
            pk[j] = (o < DSQ && c < DSQ) ? f2bf(w2[o * DSQ + c]) : (short)0;
        }
        *reinterpret_cast<short8v*>(&A2[o * 64 + (ch0 ^ ((o & 7) << 3))]) = pk;
    }
    // B2 zero-fill (linear; written masked later)
    {
        const short8v z = {0, 0, 0, 0, 0, 0, 0, 0};
        for (int idx = tid; idx < 64 * 8; idx += 1024)
            *reinterpret_cast<short8v*>(&B2[idx * 8]) = z;
    }
    // B1 pad cols [49..64) zero
    for (int idx = tid; idx < 64 * 15; idx += 1024) {
        const int p = idx / 15, c = DSQ + idx % 15;
        B1[p * 192 + (c ^ ((p & 7) << 3))] = 0;
    }
    // params
    for (int idx = tid; idx < 256; idx += 1024) {
        const int a = idx >> 6, i = idx & 63;
        float v = 0.f;
        if (i < DSQ) {
            if (a == 0) v = b1[i];
            else if (a == 1) v = lnw[i];
            else if (a == 2) v = lnb[i];
            else v = b2[i];
        }
        prm[a * 64 + i] = v;
    }
    // fSem f32 [c][p] (coalesced)
    {
        const float* srow = sem + (b * CDIM * HH + h) * WW;
        for (int idx = tid; idx < CDIM * 16; idx += 1024) {
            const int r = idx >> 4, pos = idx & 15;
            *reinterpret_cast<float4*>(&fSem[r * WW + pos * 4]) =
                *reinterpret_cast<const float4*>(&srow[r * HH * WW + pos * 4]);
        }
    }
    // softmax * spatial kernel -> sCmb f32 + B1 cmb-cols bf16
    {
        float rv[DSQ];
        #pragma unroll
        for (int n = 0; n < DSQ; ++n) rv[n] = sSim[n][l];
        float m = -1e30f;
        #pragma unroll
        for (int n = 0; n < DSQ; ++n) m = fmaxf(m, rv[n]);
        float ssum = 0.f;
        #pragma unroll
        for (int n = 0; n < DSQ; ++n) ssum += __expf(rv[n] - m);
        const float inv = 1.0f / ssum;
        const float sigma = sigma_p[0];
        const float inv2s2 = 1.0f / (2.0f * sigma * sigma);
        const int swl = (l & 7) << 3;
        #pragma unroll
        for (int k = 0; k < 4; ++k) {
            const int n = q + 16 * k;
            if (n < DSQ) {
                const int ki = n / 7, kj = n % 7;
                const float dx = (float)(ki - 3) * (1.0f / 3.0f);
                const float dy = (float)(kj - 3) * (1.0f / 3.0f);
                const float sk = __expf(-(dx * dx + dy * dy) * inv2s2);
                const float cv = __expf(rv[n] - m) * inv * sk;
                sCmb[n][l] = cv;
                B1[l * 192 + (n ^ swl)] = f2bf(cv);
            }
        }
    }
    __syncthreads();
    // B1 sem-cols: transpose-pack from fSem
    {
        const int c0 = q * 8;
        short8v pk;
        #pragma unroll
        for (int j = 0; j < 8; ++j) pk[j] = f2bf(fSem[(c0 + j) * WW + l]);
        *reinterpret_cast<short8v*>(&B1[l * 192 + ((64 + c0) ^ ((l & 7) << 3))]) = pk;
    }
    __syncthreads();

    // ---- fixup conv1 MFMA: [64 o x 192] x [192 x 64 px] ----
    const int oA = tm * 16 + lm;
    const int aswz = (oA & 7) << 3;
    const int p = tn * 16 + lm;
    const int bswz = (p & 7) << 3;

    float4v acc = {0.f, 0.f, 0.f, 0.f};
    #pragma unroll
    for (int kk = 0; kk < 6; ++kk) {
        const int ki = kk * 32 + g * 8;
        const short8v af = *reinterpret_cast<const short8v*>(&A1[oA * 192 + (ki ^ aswz)]);
        const short8v bf = *reinterpret_cast<const short8v*>(&B1[p * 192 + (ki ^ bswz)]);
        acc = __builtin_amdgcn_mfma_f32_16x16x32_bf16(af, bf, acc, 0, 0, 0);
    }
    // bias + LN(49) partials
    float vals[4];
    float s1 = 0.f, s2 = 0.f;
    #pragma unroll
    for (int r = 0; r < 4; ++r) {
        const int o = tm * 16 + g * 4 + r;
        const float v = acc[r] + prm[o];
        vals[r] = v;
        if (o < DSQ) { s1 += v; s2 += v * v; }
    }
    red1[tm * 4 + g][p] = s1;
    red2[tm * 4 + g][p] = s2;
    __syncthreads();
    float t1 = 0.f, t2 = 0.f;
    #pragma unroll
    for (int j = 0; j < 16; ++j) { t1 += red1[j][p]; t2 += red2[j][p]; }
    const float mean = t1 * (1.0f / 49.0f);
    const float var  = t2 * (1.0f / 49.0f) - mean * mean;
    const float rstd = rsqrtf(var + 1e-6f);
    #pragma unroll
    for (int r = 0; r < 4; ++r) {
        const int o = tm * 16 + g * 4 + r;
        if (o < DSQ) {
            const float v = (vals[r] - mean) * rstd * prm[64 + o] + prm[128 + o];
            const float sv = v * sigm(v);
            B2[p * 64 + (o ^ bswz)] = f2bf(sv);
        }
    }
    __syncthreads();

    // ---- fixup conv2 MFMA: [64 o x 64] x [64 x 64 px] ----
    float4v acc2 = {0.f, 0.f, 0.f, 0.f};
    #pragma unroll
    for (int kk = 0; kk < 2; ++kk) {
        const int ki = kk * 32 + g * 8;
        const short8v af = *reinterpret_cast<const short8v*>(&A2[oA * 64 + (ki ^ aswz)]);
        const short8v bf = *reinterpret_cast<const short8v*>(&B2[p * 64 + (ki ^ bswz)]);
        acc2 = __builtin_amdgcn_mfma_f32_16x16x32_bf16(af, bf, acc2, 0, 0, 0);
    }
    // gate + normalize
    float c2v[4];
    float ps = 0.f;
    #pragma unroll
    for (int r = 0; r < 4; ++r) {
        const int o = tm * 16 + g * 4 + r;
        if (o < DSQ) {
            const float f = acc2[r] + prm[192 + o];
            c2v[r] = sCmb[o][p] * (1.0f + sigm(f));
            ps += c2v[r];
        } else c2v[r] = 0.f;
    }
    red1[tm * 4 + g][p] = ps;
    __syncthreads();
    float tot = 0.f;
    #pragma unroll
    for (int j = 0; j < 16; ++j) tot += red1[j][p];
    const float invt = 1.0f / (tot + 1e-7f);
    float* wrow = wts + (b * DSQ * HH + h) * WW;
    #pragma unroll
    for (int r = 0; r < 4; ++r) {
        const int o = tm * 16 + g * 4 + r;
        if (o < DSQ) wrow[o * HH * WW + p] = c2v[r] * invt;
    }
}

// ---- fused: aggregate -> (bf16 sXT) -> output_proj conv-LN-conv MFMA -> d_out
__global__ __launch_bounds__(1024) void aggproj_kernel(
    const float* __restrict__ spatial, const float* __restrict__ wts,
    const float* __restrict__ w1, const float* __restrict__ b1,
    const float* __restrict__ lnw, const float* __restrict__ lnb,
    const float* __restrict__ w2, const float* __restrict__ b2,
    float* __restrict__ out)
{
    __shared__ alignas(16) char sBufC[32 * DD * WW * 4];   // 57.3 KB: sS | sT
    __shared__ short sWb[CDIM * CDIM];
    __shared__ short sXT[WW * CDIM];
    __shared__ short sXT2[WW * CDIM];
    __shared__ float red1[16][WW];
    __shared__ float red2[16][WW];

    float (*sS)[DD * WW] = reinterpret_cast<float(*)[DD * WW]>(sBufC);
    float (*sT)[65]      = reinterpret_cast<float(*)[65]>(sBufC);

    const int tid = threadIdx.x;
    const int l = tid & 63;
    const int q = tid >> 6;
    const int qu = __builtin_amdgcn_readfirstlane(q);
    const int b = blockIdx.x >> 6;
    const int h = blockIdx.x & 63;

    {
        const int o = tid >> 3;
        const int i0 = (tid & 7) * 16;
        const int sw = (o & 7) << 3;
        const float* src = w1 + o * CDIM + i0;
        short8v pk0, pk1;
        #pragma unroll
        for (int j = 0; j < 8; ++j) pk0[j] = f2bf(src[j]);
        #pragma unroll
        for (int j = 0; j < 8; ++j) pk1[j] = f2bf(src[8 + j]);
        *reinterpret_cast<short8v*>(&sWb[o * 128 + (i0 ^ sw)]) = pk0;
        *reinterpret_cast<short8v*>(&sWb[o * 128 + ((i0 + 8) ^ sw)]) = pk1;
    }
    float wv[DSQ];
    {
        const float* wrow = wts + (b * DSQ * HH + h) * WW + l;
        #pragma unroll
        for (int n = 0; n < DSQ; ++n) wv[n] = wrow[n * HH * WW];
    }
    int coff[DD];
    #pragma unroll
    for (int kj = 0; kj < DD; ++kj) coff[kj] = reflect64(l + kj - RR);

    const float* sb = spatial + b * CDIM * HH * WW;
    for (int cc = 0; cc < 4; ++cc) {
        __syncthreads();
        for (int idx = tid; idx < 32 * DD * 16; idx += 1024) {
            const int pos = idx & 15;
            const int rk  = idx >> 4;
            const int cl  = rk / 7;
            const int ki  = rk - cl * 7;
            const int hp  = reflect64(h + ki - RR);
            *reinterpret_cast<float4*>(&sS[cl][ki * WW + pos * 4]) =
                *reinterpret_cast<const float4*>(
                    &sb[(cc * 32 + cl) * HH * WW + hp * WW + pos * 4]);
        }
        __syncthreads();
        float acc0 = 0.f, acc1 = 0.f;
        const int c0 = q * 2;
        #pragma unroll
        for (int n = 0; n < DSQ; ++n) {
            const int ki = n / 7, kj = n % 7;
            const int off = ki * WW + coff[kj];
            acc0 = fmaf(sS[c0][off],     wv[n], acc0);
            acc1 = fmaf(sS[c0 + 1][off], wv[n], acc1);
        }
        const int cg = cc * 32 + c0;
        const int p = l, psw = (p & 7) << 3;
        sXT[p * 128 + (cg ^ psw)]       = f2bf(acc0);
        sXT[p * 128 + ((cg + 1) ^ psw)] = f2bf(acc1);
    }
    __syncthreads();

    const int lm = l & 15, g = l >> 4;
    const int tm = q >> 1;
    const int tn0 = (q & 1) * 2;
    const int oa = tm * 16 + lm;
    const int arow = oa * 128, asw = (oa & 7) << 3;
    const int p0 = tn0 * 16 + lm, p1 = (tn0 + 1) * 16 + lm;
    const int bsw0 = (p0 & 7) << 3, bsw1 = (p1 & 7) << 3;

    float4v acc0 = {0.f, 0.f, 0.f, 0.f}, acc1 = {0.f, 0.f, 0.f, 0.f};
    #pragma unroll
    for (int kk = 0; kk < 4; ++kk) {
        const int ki = kk * 32 + g * 8;
        const short8v af = *reinterpret_cast<const short8v*>(&sWb[arow + (ki ^ asw)]);
        const short8v bf0 = *reinterpret_cast<const short8v*>(&sXT[p0 * 128 + (ki ^ bsw0)]);
        const short8v bf1 = *reinterpret_cast<const short8v*>(&sXT[p1 * 128 + (ki ^ bsw1)]);
        acc0 = __builtin_amdgcn_mfma_f32_16x16x32_bf16(af, bf0, acc0, 0, 0, 0);
        acc1 = __builtin_amdgcn_mfma_f32_16x16x32_bf16(af, bf1, acc1, 0, 0, 0);
    }
    #pragma unroll
    for (int r = 0; r < 4; ++r) sT[tm * 16 + g * 4 + r][p0] = acc0[r];
    #pragma unroll
    for (int r = 0; r < 4; ++r) sT[tm * 16 + g * 4 + r][p1] = acc1[r];
    __syncthreads();

    {
        const int o = tid >> 3;
        const int i0 = (tid & 7) * 16;
        const int sw = (o & 7) << 3;
        const float* src = w2 + o * CDIM + i0;
        short8v pk0, pk1;
        #pragma unroll
        for (int j = 0; j < 8; ++j) pk0[j] = f2bf(src[j]);
        #pragma unroll
        for (int j = 0; j < 8; ++j) pk1[j] = f2bf(src[8 + j]);
        *reinterpret_cast<short8v*>(&sWb[o * 128 + (i0 ^ sw)]) = pk0;
        *reinterpret_cast<short8v*>(&sWb[o * 128 + ((i0 + 8) ^ sw)]) = pk1;
    }
    {
        const int p = l;
        float vals[8];
        float s1 = 0.f, s2 = 0.f;
        #pragma unroll
        for (int j = 0; j < 8; ++j) {
            const float v = sT[qu * 8 + j][p] + b1[qu * 8 + j];
            vals[j] = v; s1 += v; s2 += v * v;
        }
        red1[q][p] = s1; red2[q][p] = s2;
        __syncthreads();
        float t1 = 0.f, t2 = 0.f;
        #pragma unroll
        for (int j = 0; j < 16; ++j) { t1 += red1[j][p]; t2 += red2[j][p]; }
        const float mean = t1 * (1.0f / 128.0f);
        const float var  = t2 * (1.0f / 128.0f) - mean * mean;
        const float rstd = rsqrtf(var + 1e-6f);
        short8v pk;
        #pragma unroll
        for (int j = 0; j < 8; ++j) {
            const float v = (vals[j] - mean) * rstd * lnw[qu * 8 + j] + lnb[qu * 8 + j];
            pk[j] = f2bf(v);
        }
        *reinterpret_cast<short8v*>(&sXT2[p * 128 + ((qu * 8) ^ ((p & 7) << 3))]) = pk;
    }
    __syncthreads();

    {
        float4v a0 = {0.f, 0.f, 0.f, 0.f}, a1 = {0.f, 0.f, 0.f, 0.f};
        #pragma unroll
        for (int kk = 0; kk < 4; ++kk) {
            const int ki = kk * 32 + g * 8;
            const short8v af = *reinterpret_cast<const short8v*>(&sWb[arow + (ki ^ asw)]);
            const short8v bf0 = *reinterpret_cast<const short8v*>(&sXT2[p0 * 128 + (ki ^ bsw0)]);
            const short8v bf1 = *reinterpret_cast<const short8v*>(&sXT2[p1 * 128 + (ki ^ bsw1)]);
            a0 = __builtin_amdgcn_mfma_f32_16x16x32_bf16(af, bf0, a0, 0, 0, 0);
            a1 = __builtin_amdgcn_mfma_f32_16x16x32_bf16(af, bf1, a1, 0, 0, 0);
        }
        const float4 bv = *reinterpret_cast<const float4*>(&b2[tm * 16 + g * 4]);
        float* obase = out + (b * CDIM * HH + h) * WW;
        #pragma unroll
        for (int r = 0; r < 4; ++r) {
            const float bias = ((const float*)&bv)[r];
            obase[(tm * 16 + g * 4 + r) * HH * WW + p0] = a0[r] + bias;
            obase[(tm * 16 + g * 4 + r) * HH * WW + p1] = a1[r] + bias;
        }
    }
}

extern "C" void kernel_launch(void* const* d_in, const int* in_sizes, int n_in,
                              void* d_out, int out_size, void* d_ws, size_t ws_size,
                              hipStream_t stream) {
    (void)in_sizes; (void)n_in; (void)out_size; (void)ws_size;
    const float* spatial  = (const float*)d_in[0];
    const float* semantic = (const float*)d_in[1];
    const float* rp_w1 = (const float*)d_in[2];
    const float* rp_b1 = (const float*)d_in[3];
    const float* rp_lnw = (const float*)d_in[4];
    const float* rp_lnb = (const float*)d_in[5];
    const float* rp_w2 = (const float*)d_in[6];
    const float* rp_b2 = (const float*)d_in[7];
    const float* fx_w1 = (const float*)d_in[8];
    const float* fx_b1 = (const float*)d_in[9];
    const float* fx_lnw = (const float*)d_in[10];
    const float* fx_lnb = (const float*)d_in[11];
    const float* fx_w2 = (const float*)d_in[12];
    const float* fx_b2 = (const float*)d_in[13];
    const float* sigma = (const float*)d_in[14];
    const float* op_w1 = (const float*)d_in[15];
    const float* op_b1 = (const float*)d_in[16];
    const float* op_lnw = (const float*)d_in[17];
    const float* op_lnb = (const float*)d_in[18];
    const float* op_w2 = (const float*)d_in[19];
    const float* op_b2 = (const float*)d_in[20];

    char* wsb = (char*)d_ws;
    short* pxt    = (short*)wsb;                             // 4 MB bf16 [b][h][p][c]
    float* wtsbuf = (float*)(wsb + 4u * 1024u * 1024u);      // 3.2 MB
    float* outp   = (float*)d_out;

    dim3 grid(BB * HH), blk(1024);
    proj_kernel<true><<<grid, blk, 0, stream>>>(semantic, rp_w1, rp_b1, rp_lnw, rp_lnb,
                                                rp_w2, rp_b2, pxt);
    simfix_kernel<<<grid, blk, 0, stream>>>(pxt, sigma, semantic, fx_w1, fx_b1,
                                            fx_lnw, fx_lnb, fx_w2, fx_b2, wtsbuf);
    aggproj_kernel<<<grid, blk, 0, stream>>>(spatial, wtsbuf, op_w1, op_b1, op_lnw,
                                             op_lnb, op_w2, op_b2, outp);
}